// Round 1
// baseline (2577.441 us; speedup 1.0000x reference)
//
#include <hip/hip_runtime.h>

#define NN 2048   // sequence length
#define CC 512    // channels
// B=4, H=8, D=64

// ---------------------------------------------------------------------------
// GEMM: Y[b,o,n] = bias[o] + sum_{c<K} W[o,c] * X(b,c,n)  (+ optional residual)
// X(b,c,n) = c < Ca ? Xa[b,c,n] : Xb[b,c-Ca,n]   (virtual concat, no copy)
// Tiles: 64(o) x 64(n) x 16(k); block 16x16, each thread 4x4.
// ---------------------------------------------------------------------------
__global__ __launch_bounds__(256) void gemm_conv(
    const float* __restrict__ W, const float* __restrict__ bias,
    const float* __restrict__ Xa, const float* __restrict__ Xb,
    int Ca, int K, const float* __restrict__ Rres,
    float* __restrict__ Y, int Cout)
{
    __shared__ float Ws[16][68];   // [k][o], transposed stage
    __shared__ float Xs[16][68];   // [k][n]
    const int tx = threadIdx.x, ty = threadIdx.y;
    const int tid = ty * 16 + tx;
    const int b  = blockIdx.z;
    const int o0 = blockIdx.y * 64, n0 = blockIdx.x * 64;
    const int w_or = tid >> 2, w_kg = tid & 3;    // W stage: 64 rows x 4 k-groups
    const int x_kr = tid >> 4, x_c4 = tid & 15;   // X stage: 16 k-rows x 16 float4
    const int Cb = K - Ca;

    float acc[4][4] = {};
    for (int k0 = 0; k0 < K; k0 += 16) {
        float4 wv = *(const float4*)&W[(size_t)(o0 + w_or) * K + k0 + w_kg * 4];
        Ws[w_kg * 4 + 0][w_or] = wv.x;
        Ws[w_kg * 4 + 1][w_or] = wv.y;
        Ws[w_kg * 4 + 2][w_or] = wv.z;
        Ws[w_kg * 4 + 3][w_or] = wv.w;
        int c = k0 + x_kr;
        const float* Xp = (c < Ca) ? (Xa + ((size_t)b * Ca + c) * NN)
                                   : (Xb + ((size_t)b * Cb + (c - Ca)) * NN);
        *(float4*)&Xs[x_kr][x_c4 * 4] = *(const float4*)&Xp[n0 + x_c4 * 4];
        __syncthreads();
#pragma unroll
        for (int kk = 0; kk < 16; ++kk) {
            float4 wr = *(const float4*)&Ws[kk][ty * 4];
            float4 xr = *(const float4*)&Xs[kk][tx * 4];
            float w[4] = {wr.x, wr.y, wr.z, wr.w};
            float x[4] = {xr.x, xr.y, xr.z, xr.w};
#pragma unroll
            for (int i = 0; i < 4; ++i)
#pragma unroll
                for (int j = 0; j < 4; ++j)
                    acc[i][j] = fmaf(w[i], x[j], acc[i][j]);
        }
        __syncthreads();
    }
#pragma unroll
    for (int i = 0; i < 4; ++i) {
        int o = o0 + ty * 4 + i;
        float bs = bias[o];
        size_t base = ((size_t)b * Cout + o) * NN + n0 + tx * 4;
        float4 yv;
        if (Rres) {
            float4 r = *(const float4*)&Rres[base];
            yv.x = acc[i][0] + bs + r.x; yv.y = acc[i][1] + bs + r.y;
            yv.z = acc[i][2] + bs + r.z; yv.w = acc[i][3] + bs + r.w;
        } else {
            yv.x = acc[i][0] + bs; yv.y = acc[i][1] + bs;
            yv.z = acc[i][2] + bs; yv.w = acc[i][3] + bs;
        }
        *(float4*)&Y[base] = yv;
    }
}

// ---------------------------------------------------------------------------
// Flash attention per (b,h): Q,K,V laid out as [B, D*H, N] with channel d*8+h.
// Block = 64 queries; online softmax over 32 key tiles of 64.
// Ks and Ps alias one LDS buffer (extra barrier between S-GEMM and P-write).
// ---------------------------------------------------------------------------
__global__ __launch_bounds__(256) void flash_attn(
    const float* __restrict__ Q, const float* __restrict__ K,
    const float* __restrict__ V, float* __restrict__ O)
{
    __shared__ float Qs[64][68];   // [d][n]
    __shared__ float KP[64][68];   // phase 1: Ks[d][m]; phase 2: Ps[n][m]
    __shared__ float Vs[64][65];   // [d][m], odd stride for column reads
    const int tx = threadIdx.x, ty = threadIdx.y;
    const int tid = ty * 16 + tx;
    const int n0 = blockIdx.x * 64;
    const int h = blockIdx.y, b = blockIdx.z;
    const size_t base = ((size_t)b * CC + h) * NN;   // + d*sD + n
    const int sD = 8 * NN;
    const int sr = tid >> 4, sc4 = tid & 15;

#pragma unroll
    for (int it = 0; it < 4; ++it) {
        int d = sr + it * 16;
        *(float4*)&Qs[d][sc4 * 4] = *(const float4*)&Q[base + (size_t)d * sD + n0 + sc4 * 4];
    }

    float mrun[4], l[4], o[4][4];
#pragma unroll
    for (int i = 0; i < 4; ++i) {
        mrun[i] = -1e30f; l[i] = 0.f;
#pragma unroll
        for (int j = 0; j < 4; ++j) o[i][j] = 0.f;
    }

    for (int m0 = 0; m0 < NN; m0 += 64) {
#pragma unroll
        for (int it = 0; it < 4; ++it) {
            int d = sr + it * 16;
            *(float4*)&KP[d][sc4 * 4] = *(const float4*)&K[base + (size_t)d * sD + m0 + sc4 * 4];
            float4 vv = *(const float4*)&V[base + (size_t)d * sD + m0 + sc4 * 4];
            Vs[d][sc4 * 4 + 0] = vv.x; Vs[d][sc4 * 4 + 1] = vv.y;
            Vs[d][sc4 * 4 + 2] = vv.z; Vs[d][sc4 * 4 + 3] = vv.w;
        }
        __syncthreads();

        // S = (Q^T K) / 8 ; thread owns rows n=ty*4.., cols m=tx*4..
        float s[4][4] = {};
        for (int d = 0; d < 64; ++d) {
            float4 qr = *(const float4*)&Qs[d][ty * 4];
            float4 kr = *(const float4*)&KP[d][tx * 4];
            float q[4] = {qr.x, qr.y, qr.z, qr.w};
            float k[4] = {kr.x, kr.y, kr.z, kr.w};
#pragma unroll
            for (int i = 0; i < 4; ++i)
#pragma unroll
                for (int j = 0; j < 4; ++j)
                    s[i][j] = fmaf(q[i], k[j], s[i][j]);
        }
        __syncthreads();   // all Ks reads done before P overwrites the buffer

        // online softmax update
        float alpha[4];
#pragma unroll
        for (int i = 0; i < 4; ++i) {
#pragma unroll
            for (int j = 0; j < 4; ++j) s[i][j] *= 0.125f;
            float mx = fmaxf(fmaxf(s[i][0], s[i][1]), fmaxf(s[i][2], s[i][3]));
#pragma unroll
            for (int off = 1; off < 16; off <<= 1)
                mx = fmaxf(mx, __shfl_xor(mx, off));
            float mnew = fmaxf(mrun[i], mx);
            alpha[i] = __expf(mrun[i] - mnew);
            mrun[i] = mnew;
            float rs = 0.f;
#pragma unroll
            for (int j = 0; j < 4; ++j) {
                float pv = __expf(s[i][j] - mnew);
                KP[ty * 4 + i][tx * 4 + j] = pv;   // Ps[n][m]
                rs += pv;
            }
#pragma unroll
            for (int off = 1; off < 16; off <<= 1)
                rs += __shfl_xor(rs, off);
            l[i] = l[i] * alpha[i] + rs;
        }
#pragma unroll
        for (int i = 0; i < 4; ++i)
#pragma unroll
            for (int j = 0; j < 4; ++j) o[i][j] *= alpha[i];
        __syncthreads();   // Ps visible to all

        // O[n][d] += P[n][m] * V[d][m] ; thread owns rows n=ty*4.., cols d=tx*4..
        for (int m = 0; m < 64; ++m) {
            float pv[4], vv[4];
#pragma unroll
            for (int i = 0; i < 4; ++i) pv[i] = KP[ty * 4 + i][m];
#pragma unroll
            for (int j = 0; j < 4; ++j) vv[j] = Vs[tx * 4 + j][m];
#pragma unroll
            for (int i = 0; i < 4; ++i)
#pragma unroll
                for (int j = 0; j < 4; ++j)
                    o[i][j] = fmaf(pv[i], vv[j], o[i][j]);
        }
        __syncthreads();   // protect KP/Vs before next tile's staging
    }

    float invl[4];
#pragma unroll
    for (int i = 0; i < 4; ++i) invl[i] = 1.f / l[i];
#pragma unroll
    for (int j = 0; j < 4; ++j)
#pragma unroll
        for (int i = 0; i < 4; ++i)
            O[base + (size_t)(tx * 4 + j) * sD + n0 + ty * 4 + i] = o[i][j] * invl[i];
}

// ---------------------------------------------------------------------------
// Instance norm over N per (b,channel), then ReLU, in place. One block per row.
// ---------------------------------------------------------------------------
__global__ __launch_bounds__(256) void inorm_relu(float* __restrict__ X)
{
    const size_t row = blockIdx.x;
    float* p = X + row * NN;
    const int tid = threadIdx.x;
    float4 v0 = *(const float4*)&p[tid * 4];
    float4 v1 = *(const float4*)&p[tid * 4 + 1024];
    float s  = v0.x + v0.y + v0.z + v0.w + v1.x + v1.y + v1.z + v1.w;
    float s2 = v0.x*v0.x + v0.y*v0.y + v0.z*v0.z + v0.w*v0.w
             + v1.x*v1.x + v1.y*v1.y + v1.z*v1.z + v1.w*v1.w;
#pragma unroll
    for (int off = 1; off < 64; off <<= 1) {
        s  += __shfl_xor(s,  off);
        s2 += __shfl_xor(s2, off);
    }
    __shared__ float redS[4], redS2[4];
    if ((tid & 63) == 0) { redS[tid >> 6] = s; redS2[tid >> 6] = s2; }
    __syncthreads();
    float S  = redS[0]  + redS[1]  + redS[2]  + redS[3];
    float S2 = redS2[0] + redS2[1] + redS2[2] + redS2[3];
    const float invN = 1.f / (float)NN;
    float mean = S * invN;
    float var  = S2 * invN - mean * mean;
    float rstd = rsqrtf(var + 1e-5f);
    float4 o0, o1;
    o0.x = fmaxf(0.f, (v0.x - mean) * rstd); o0.y = fmaxf(0.f, (v0.y - mean) * rstd);
    o0.z = fmaxf(0.f, (v0.z - mean) * rstd); o0.w = fmaxf(0.f, (v0.w - mean) * rstd);
    o1.x = fmaxf(0.f, (v1.x - mean) * rstd); o1.y = fmaxf(0.f, (v1.y - mean) * rstd);
    o1.z = fmaxf(0.f, (v1.z - mean) * rstd); o1.w = fmaxf(0.f, (v1.w - mean) * rstd);
    *(float4*)&p[tid * 4]        = o0;
    *(float4*)&p[tid * 4 + 1024] = o1;
}

// ---------------------------------------------------------------------------
extern "C" void kernel_launch(void* const* d_in, const int* in_sizes, int n_in,
                              void* d_out, int out_size, void* d_ws, size_t ws_size,
                              hipStream_t stream)
{
    (void)in_sizes; (void)n_in; (void)out_size; (void)ws_size;
    const float* src = (const float*)d_in[0];
    const float* tgt = (const float*)d_in[1];
    const float* Wq = (const float*)d_in[2];  const float* bq = (const float*)d_in[3];
    const float* Wk = (const float*)d_in[4];  const float* bk = (const float*)d_in[5];
    const float* Wv = (const float*)d_in[6];  const float* bv = (const float*)d_in[7];
    const float* Wm = (const float*)d_in[8];  const float* bm = (const float*)d_in[9];
    const float* W1 = (const float*)d_in[10]; const float* b1 = (const float*)d_in[11];
    const float* W2 = (const float*)d_in[12]; const float* b2 = (const float*)d_in[13];
    float* out = (float*)d_out;
    float* ws  = (float*)d_ws;
    const size_t R = (size_t)4 * CC * NN;   // 16 MiB region (floats)

    dim3 blk(16, 16);
    auto run_half = [&](const float* a, const float* kv, float* yout) {
        float* q   = ws;
        float* kk  = ws + R;
        float* vv  = ws + 2 * R;
        float* att = ws + 3 * R;
        gemm_conv<<<dim3(32, 8, 4),  blk, 0, stream>>>(Wq, bq, a,  nullptr, CC, CC, nullptr, q,  CC);
        gemm_conv<<<dim3(32, 8, 4),  blk, 0, stream>>>(Wk, bk, kv, nullptr, CC, CC, nullptr, kk, CC);
        gemm_conv<<<dim3(32, 8, 4),  blk, 0, stream>>>(Wv, bv, kv, nullptr, CC, CC, nullptr, vv, CC);
        flash_attn<<<dim3(32, 8, 4), blk, 0, stream>>>(q, kk, vv, att);
        float* satt = ws;          // reuse q region
        gemm_conv<<<dim3(32, 8, 4),  blk, 0, stream>>>(Wm, bm, att, nullptr, CC, CC, nullptr, satt, CC);
        float* hid = ws + R;       // 2 contiguous regions [B, 2C, N]
        gemm_conv<<<dim3(32, 16, 4), blk, 0, stream>>>(W1, b1, a, satt, CC, 2 * CC, nullptr, hid, 2 * CC);
        inorm_relu<<<dim3(4 * 2 * CC), dim3(256), 0, stream>>>(hid);
        gemm_conv<<<dim3(32, 8, 4),  blk, 0, stream>>>(W2, b2, hid, nullptr, 2 * CC, 2 * CC, a, yout, CC);
    };

    run_half(src, tgt, out);        // src update (uses original tgt)
    run_half(tgt, out, out + R);    // tgt update (uses UPDATED src from d_out)
}

// Round 2
// 600.503 us; speedup vs baseline: 4.2921x; 4.2921x over previous
//
#include <hip/hip_runtime.h>

#define NN 2048
#define CC 512
#define BB 4
#define HH 8
#define DD 64

typedef unsigned short u16;
typedef __attribute__((ext_vector_type(8))) short bf16x8;   // 8 bf16 (4 VGPRs)
typedef __attribute__((ext_vector_type(4))) float f32x4;    // MFMA accumulator

__device__ inline u16 f2b(float x) {           // fp32 -> bf16 (RNE)
    unsigned u = __builtin_bit_cast(unsigned, x);
    u += 0x7fffu + ((u >> 16) & 1u);
    return (u16)(u >> 16);
}
__device__ inline float b2f(u16 h) {
    unsigned u = ((unsigned)h) << 16;
    return __builtin_bit_cast(float, u);
}

#define GLD16(g, l) __builtin_amdgcn_global_load_lds( \
    (const __attribute__((address_space(1))) unsigned int*)(g), \
    (__attribute__((address_space(3))) unsigned int*)(l), 16, 0, 0)

// ---------------------------------------------------------------------------
// bf16 MFMA GEMM:  Y[n][o] = sum_k X[n][k] * W[o][k]  (+bias, modes below)
// X = virtual concat(Xa [.., Ca], Xb [.., K-Ca]) along k, both [B,N,*] bf16.
// Tile 128(n) x 128(o) x 32(k); 4 waves in 2x2; 16 MFMA 16x16x32 per wave/step.
// mode 0: outB bf16 [B,N,Cout]
// mode 1: outB bf16 [B,H,D,N]   (V layout; Cout=512, o=(h<<6)|d)
// mode 2: outF fp32 [B,Cout,N] = acc+bias+res, AND outB bf16 [B,N,Cout]
// mode 3: outF fp32 only
// ---------------------------------------------------------------------------
__global__ __launch_bounds__(256) void gemm_bf16(
    const u16* __restrict__ Wb, const float* __restrict__ bias,
    const u16* __restrict__ Xa, const u16* __restrict__ Xb,
    int Ca, int K, int Cout,
    const float* __restrict__ res, float* __restrict__ outF,
    u16* __restrict__ outB, int mode)
{
    __shared__ u16 As[128 * 32];
    __shared__ u16 Bs[128 * 32];
    const int tid = threadIdx.x;
    const int lane = tid & 63, w = tid >> 6;
    const int quad = lane >> 4, l16 = lane & 15;
    const int wrow = w & 1, wcol = w >> 1;
    const int b = blockIdx.z;
    const int n0 = blockIdx.x * 128, o0 = blockIdx.y * 128;
    const int arow = lane >> 2, aseg = lane & 3;   // staging: 16 rows x 4x16B
    const size_t bN = (size_t)b * NN;

    f32x4 acc[4][4] = {};

    for (int k0 = 0; k0 < K; k0 += 32) {
        const u16* Xs; int Crow, cc;
        if (k0 < Ca) { Xs = Xa; Crow = Ca; cc = k0; }
        else         { Xs = Xb; Crow = K - Ca; cc = k0 - Ca; }
#pragma unroll
        for (int i = 0; i < 2; ++i) {
            int rl = w * 32 + i * 16 + arow;
            int la = __builtin_amdgcn_readfirstlane((w * 32 + i * 16) * 32);
            const u16* ga = Xs + ((bN + n0 + rl) * (size_t)Crow + cc) + aseg * 8;
            GLD16(ga, (char*)As + (size_t)la * 2);
            const u16* gb = Wb + ((size_t)(o0 + rl) * K + k0) + aseg * 8;
            GLD16(gb, (char*)Bs + (size_t)la * 2);
        }
        __syncthreads();
        bf16x8 av[4], bv[4];
#pragma unroll
        for (int i = 0; i < 4; ++i)
            av[i] = *(const bf16x8*)&As[(wrow * 64 + i * 16 + l16) * 32 + quad * 8];
#pragma unroll
        for (int j = 0; j < 4; ++j)
            bv[j] = *(const bf16x8*)&Bs[(wcol * 64 + j * 16 + l16) * 32 + quad * 8];
#pragma unroll
        for (int i = 0; i < 4; ++i)
#pragma unroll
            for (int j = 0; j < 4; ++j)
                acc[i][j] = __builtin_amdgcn_mfma_f32_16x16x32_bf16(av[i], bv[j], acc[i][j], 0, 0, 0);
        __syncthreads();
    }

    const int nb0 = n0 + wrow * 64, ob0 = o0 + wcol * 64;
    if (mode == 0) {
#pragma unroll
        for (int j = 0; j < 4; ++j) {
            int o = ob0 + j * 16 + l16;
            float bs = bias[o];
#pragma unroll
            for (int i = 0; i < 4; ++i)
#pragma unroll
                for (int r = 0; r < 4; ++r) {
                    int n = nb0 + i * 16 + quad * 4 + r;
                    outB[(bN + n) * Cout + o] = f2b(acc[i][j][r] + bs);
                }
        }
    } else if (mode == 1) {
#pragma unroll
        for (int j = 0; j < 4; ++j) {
            int o = ob0 + j * 16 + l16;
            float bs = bias[o];
            int h = o >> 6, d = o & 63;
#pragma unroll
            for (int i = 0; i < 4; ++i) {
                int n = nb0 + i * 16 + quad * 4;
                ushort4 pk;
                pk.x = f2b(acc[i][j][0] + bs); pk.y = f2b(acc[i][j][1] + bs);
                pk.z = f2b(acc[i][j][2] + bs); pk.w = f2b(acc[i][j][3] + bs);
                *(ushort4*)&outB[(((size_t)b * HH + h) * DD + d) * NN + n] = pk;
            }
        }
    } else {
#pragma unroll
        for (int j = 0; j < 4; ++j) {
            int o = ob0 + j * 16 + l16;
            float bs = bias[o];
#pragma unroll
            for (int i = 0; i < 4; ++i) {
                int n = nb0 + i * 16 + quad * 4;
                size_t ad = ((size_t)b * Cout + o) * NN + n;
                float4 rv = *(const float4*)&res[ad];
                float4 yv;
                yv.x = acc[i][j][0] + bs + rv.x;
                yv.y = acc[i][j][1] + bs + rv.y;
                yv.z = acc[i][j][2] + bs + rv.z;
                yv.w = acc[i][j][3] + bs + rv.w;
                *(float4*)&outF[ad] = yv;
                if (mode == 2) {
                    outB[(bN + n + 0) * Cout + o] = f2b(yv.x);
                    outB[(bN + n + 1) * Cout + o] = f2b(yv.y);
                    outB[(bN + n + 2) * Cout + o] = f2b(yv.z);
                    outB[(bN + n + 3) * Cout + o] = f2b(yv.w);
                }
            }
        }
    }
}

// ---------------------------------------------------------------------------
// Flash attention, MFMA. Q,K: [B,N,512] bf16 head-major (c' = h*64+d).
// V: [B,H,D,N] bf16. Out: [B,N,512] bf16.
// Block = 128 q-rows (4 waves x 32), m-tiles of 64 keys.
// Computes S^T = K*Q^T (row=m, col=n) so softmax stats reduce with 2 shfls and
// P packs to LDS as 8B writes in [n][m-contig] (A-operand layout for PV).
// All LDS tiles padded to stride 72 to break 128B bank aliasing.
// ---------------------------------------------------------------------------
__global__ __launch_bounds__(256) void attn(
    const u16* __restrict__ Qg, const u16* __restrict__ Kg,
    const u16* __restrict__ Vg, u16* __restrict__ Og)
{
    __shared__ u16 Ks[64 * 72];
    __shared__ u16 Vt[64 * 72];
    __shared__ u16 Ps[128 * 72];
    const int tid = threadIdx.x;
    const int lane = tid & 63, w = tid >> 6;
    const int quad = lane >> 4, l16 = lane & 15;
    const int n0 = blockIdx.x * 128;
    const int h = blockIdx.y, b = blockIdx.z;
    const int wn0 = w * 32;
    const size_t qkBase = ((size_t)b * NN) * CC + h * DD;   // + n*CC + d
    const size_t vBase  = (((size_t)b * HH + h) * DD) * NN; // + d*NN + m
    const int srow = lane >> 3, sseg = lane & 7;            // staging 8 rows x 8x16B

    // Q fragments (loop-invariant): B-operand layout, col=n, k=d
    bf16x8 qf[2][2];
#pragma unroll
    for (int ct = 0; ct < 2; ++ct) {
        int n = n0 + wn0 + ct * 16 + l16;
#pragma unroll
        for (int ks = 0; ks < 2; ++ks)
            qf[ct][ks] = *(const bf16x8*)&Qg[qkBase + (size_t)n * CC + ks * 32 + quad * 8];
    }

    float m_run[2] = {-1e30f, -1e30f}, l_run[2] = {0.f, 0.f};
    f32x4 oa[2][4] = {};

    for (int m0 = 0; m0 < NN; m0 += 64) {
#pragma unroll
        for (int i = 0; i < 2; ++i) {
            int r = w * 16 + i * 8 + srow;
            bf16x8 kv = *(const bf16x8*)&Kg[qkBase + (size_t)(m0 + r) * CC + sseg * 8];
            *(bf16x8*)&Ks[r * 72 + sseg * 8] = kv;
            bf16x8 vv = *(const bf16x8*)&Vg[vBase + (size_t)r * NN + m0 + sseg * 8];
            *(bf16x8*)&Vt[r * 72 + sseg * 8] = vv;
        }
        __syncthreads();

        // S^T = K * Q^T : 4 row-tiles (m), 2 col-tiles (n) per wave
        f32x4 st[4][2] = {};
#pragma unroll
        for (int ks = 0; ks < 2; ++ks) {
            bf16x8 ak[4];
#pragma unroll
            for (int rt = 0; rt < 4; ++rt)
                ak[rt] = *(const bf16x8*)&Ks[(rt * 16 + l16) * 72 + ks * 32 + quad * 8];
#pragma unroll
            for (int rt = 0; rt < 4; ++rt)
#pragma unroll
                for (int ct = 0; ct < 2; ++ct)
                    st[rt][ct] = __builtin_amdgcn_mfma_f32_16x16x32_bf16(ak[rt], qf[ct][ks], st[rt][ct], 0, 0, 0);
        }

        float alpha[2];
#pragma unroll
        for (int ct = 0; ct < 2; ++ct) {
            float mx = -1e30f;
#pragma unroll
            for (int rt = 0; rt < 4; ++rt)
#pragma unroll
                for (int r = 0; r < 4; ++r) {
                    st[rt][ct][r] *= 0.125f;                  // 1/sqrt(64)
                    mx = fmaxf(mx, st[rt][ct][r]);
                }
            mx = fmaxf(mx, __shfl_xor(mx, 16));
            mx = fmaxf(mx, __shfl_xor(mx, 32));
            float mn = fmaxf(m_run[ct], mx);
            alpha[ct] = __expf(m_run[ct] - mn);
            m_run[ct] = mn;
            float ls = 0.f;
            int nrow = wn0 + ct * 16 + l16;
#pragma unroll
            for (int rt = 0; rt < 4; ++rt) {
                float p0 = __expf(st[rt][ct][0] - mn);
                float p1 = __expf(st[rt][ct][1] - mn);
                float p2 = __expf(st[rt][ct][2] - mn);
                float p3 = __expf(st[rt][ct][3] - mn);
                ls += p0 + p1 + p2 + p3;
                ushort4 pk;
                pk.x = f2b(p0); pk.y = f2b(p1); pk.z = f2b(p2); pk.w = f2b(p3);
                *(ushort4*)&Ps[nrow * 72 + rt * 16 + quad * 4] = pk;   // P[n][m]
            }
            ls += __shfl_xor(ls, 16);
            ls += __shfl_xor(ls, 32);
            l_run[ct] = l_run[ct] * alpha[ct] + ls;
        }

        // rescale O by alpha (broadcast col-stat to row-layout via shfl)
#pragma unroll
        for (int rt = 0; rt < 2; ++rt)
#pragma unroll
            for (int r = 0; r < 4; ++r) {
                float ab = __shfl(alpha[rt], quad * 4 + r, 16);
#pragma unroll
                for (int ct = 0; ct < 4; ++ct)
                    oa[rt][ct][r] *= ab;
            }

        // O += P * V : A = P[n][m] (own rows, no barrier), B = V^T from Vt[d][m]
#pragma unroll
        for (int ks = 0; ks < 2; ++ks) {
            bf16x8 pa[2], vb[4];
#pragma unroll
            for (int rt = 0; rt < 2; ++rt)
                pa[rt] = *(const bf16x8*)&Ps[(wn0 + rt * 16 + l16) * 72 + ks * 32 + quad * 8];
#pragma unroll
            for (int ct = 0; ct < 4; ++ct)
                vb[ct] = *(const bf16x8*)&Vt[(ct * 16 + l16) * 72 + ks * 32 + quad * 8];
#pragma unroll
            for (int rt = 0; rt < 2; ++rt)
#pragma unroll
                for (int ct = 0; ct < 4; ++ct)
                    oa[rt][ct] = __builtin_amdgcn_mfma_f32_16x16x32_bf16(pa[rt], vb[ct], oa[rt][ct], 0, 0, 0);
        }
        __syncthreads();
    }

#pragma unroll
    for (int rt = 0; rt < 2; ++rt) {
        float li0 = 1.f / l_run[rt];
#pragma unroll
        for (int r = 0; r < 4; ++r) {
            float li = __shfl(li0, quad * 4 + r, 16);
            int n = n0 + wn0 + rt * 16 + quad * 4 + r;
#pragma unroll
            for (int ct = 0; ct < 4; ++ct)
                Og[qkBase + (size_t)n * CC + ct * 16 + l16] = f2b(oa[rt][ct][r] * li);
        }
    }
}

// ---------------------------------------------------------------------------
// fp32 [B,C,N] -> bf16 [B,N,C] transpose+convert (64x64 tiles via LDS)
// ---------------------------------------------------------------------------
__global__ __launch_bounds__(256) void transpose_cvt(
    const float* __restrict__ X, u16* __restrict__ Y)
{
    __shared__ float T[64][65];
    const int tid = threadIdx.x;
    const int n0 = blockIdx.x * 64, c0 = blockIdx.y * 64, b = blockIdx.z;
    const int rr = tid >> 4, cc4 = tid & 15;
#pragma unroll
    for (int p = 0; p < 4; ++p) {
        int cl = p * 16 + rr;
        float4 v = *(const float4*)&X[((size_t)b * CC + c0 + cl) * NN + n0 + cc4 * 4];
        T[cl][cc4 * 4 + 0] = v.x; T[cl][cc4 * 4 + 1] = v.y;
        T[cl][cc4 * 4 + 2] = v.z; T[cl][cc4 * 4 + 3] = v.w;
    }
    __syncthreads();
#pragma unroll
    for (int p = 0; p < 4; ++p) {
        int nl = p * 16 + rr;
        ushort4 pk;
        pk.x = f2b(T[cc4 * 4 + 0][nl]);
        pk.y = f2b(T[cc4 * 4 + 1][nl]);
        pk.z = f2b(T[cc4 * 4 + 2][nl]);
        pk.w = f2b(T[cc4 * 4 + 3][nl]);
        *(ushort4*)&Y[((size_t)b * NN + n0 + nl) * CC + c0 + cc4 * 4] = pk;
    }
}

// Weight fp32->bf16; perm 1 = row perm (o'=h*64+d <- d*8+h), 2 = col perm.
__global__ __launch_bounds__(256) void convW(
    const float* __restrict__ W, u16* __restrict__ out, int cols, int perm)
{
    int c = blockIdx.x * 256 + threadIdx.x;
    int r = blockIdx.y;
    int sr = r, sc = c;
    if (perm == 1) sr = (r & 63) * 8 + (r >> 6);
    else if (perm == 2) sc = (c & 63) * 8 + (c >> 6);
    out[(size_t)r * cols + c] = f2b(W[(size_t)sr * cols + sc]);
}

__global__ void biasperm(const float* __restrict__ bi, float* __restrict__ o) {
    int i = blockIdx.x * 256 + threadIdx.x;
    o[i] = bi[(i & 63) * 8 + (i >> 6)];
}

// ---------------------------------------------------------------------------
// Instance norm over N per (b,c) on bf16 [B,N,1024], two-pass via fp32 atomics
// ---------------------------------------------------------------------------
__global__ __launch_bounds__(256) void inorm_p1(
    const u16* __restrict__ X, float* __restrict__ Ssum, float* __restrict__ Ssq)
{
    __shared__ float rs[4][64], rq[4][64];
    const int tid = threadIdx.x;
    const int cl = tid & 63, g = tid >> 6;
    const int c = blockIdx.x * 64 + cl;
    const int b = blockIdx.y, nz = blockIdx.z;
    float s = 0.f, q = 0.f;
    size_t base = ((size_t)b * NN + nz * 256 + g * 64) * 1024 + c;
#pragma unroll 4
    for (int i = 0; i < 64; ++i) {
        float x = b2f(X[base + (size_t)i * 1024]);
        s += x; q += x * x;
    }
    rs[g][cl] = s; rq[g][cl] = q;
    __syncthreads();
    if (g == 0) {
        s = rs[0][cl] + rs[1][cl] + rs[2][cl] + rs[3][cl];
        q = rq[0][cl] + rq[1][cl] + rq[2][cl] + rq[3][cl];
        atomicAdd(&Ssum[b * 1024 + c], s);
        atomicAdd(&Ssq[b * 1024 + c], q);
    }
}

__global__ __launch_bounds__(256) void inorm_p2(
    u16* __restrict__ X, const float* __restrict__ Ssum, const float* __restrict__ Ssq)
{
    const int tid = threadIdx.x;
    const int cl = tid & 63, g = tid >> 6;
    const int c = blockIdx.x * 64 + cl;
    const int b = blockIdx.y, nz = blockIdx.z;
    float mean = Ssum[b * 1024 + c] * (1.f / NN);
    float var  = Ssq[b * 1024 + c] * (1.f / NN) - mean * mean;
    float rstd = rsqrtf(fmaxf(var, 0.f) + 1e-5f);
    size_t base = ((size_t)b * NN + nz * 256 + g * 64) * 1024 + c;
#pragma unroll 4
    for (int i = 0; i < 64; ++i) {
        float x = b2f(X[base + (size_t)i * 1024]);
        x = (x - mean) * rstd;
        X[base + (size_t)i * 1024] = f2b(fmaxf(x, 0.f));
    }
}

// ---------------------------------------------------------------------------
extern "C" void kernel_launch(void* const* d_in, const int* in_sizes, int n_in,
                              void* d_out, int out_size, void* d_ws, size_t ws_size,
                              hipStream_t stream)
{
    (void)in_sizes; (void)n_in; (void)out_size; (void)ws_size;
    const float* src = (const float*)d_in[0];
    const float* tgt = (const float*)d_in[1];
    const float* Wq = (const float*)d_in[2];  const float* bq = (const float*)d_in[3];
    const float* Wk = (const float*)d_in[4];  const float* bk = (const float*)d_in[5];
    const float* Wv = (const float*)d_in[6];  const float* bv = (const float*)d_in[7];
    const float* Wm = (const float*)d_in[8];  const float* bm = (const float*)d_in[9];
    const float* W1 = (const float*)d_in[10]; const float* b1 = (const float*)d_in[11];
    const float* W2 = (const float*)d_in[12]; const float* b2 = (const float*)d_in[13];

    char* w = (char*)d_ws;
    u16* WQp = (u16*)(w);
    u16* WKp = (u16*)(w + (512u << 10));
    u16* WVp = (u16*)(w + (1u << 20));
    u16* WMp = (u16*)(w + (3u << 19));        // 1.5 MB
    u16* W1b = (u16*)(w + (2u << 20));        // 2 MB
    u16* W2b = (u16*)(w + (4u << 20));        // 1 MB
    float* BQp = (float*)(w + (5u << 20));
    float* BKp = BQp + 512;
    float* BVp = BQp + 1024;
    float* STS = BQp + 1536;                  // 4096 sums
    float* STQ = STS + 4096;                  // 4096 sumsq
    u16* X0 = (u16*)(w + ( 6u << 20));        // 8 MB regions
    u16* X1 = (u16*)(w + (14u << 20));
    u16* B0 = (u16*)(w + (22u << 20));
    u16* B1 = (u16*)(w + (30u << 20));
    u16* B2 = (u16*)(w + (38u << 20));
    u16* B3 = (u16*)(w + (46u << 20));

    float* out = (float*)d_out;
    const size_t R = (size_t)BB * CC * NN;
    dim3 blk(256);

    // weight / input prep (runs every launch; ~5 MB of work)
    convW<<<dim3(2, 512), blk, 0, stream>>>(Wq, WQp, 512, 1);
    convW<<<dim3(2, 512), blk, 0, stream>>>(Wk, WKp, 512, 1);
    convW<<<dim3(2, 512), blk, 0, stream>>>(Wv, WVp, 512, 1);
    convW<<<dim3(2, 512), blk, 0, stream>>>(Wm, WMp, 512, 2);
    convW<<<dim3(4, 1024), blk, 0, stream>>>(W1, W1b, 1024, 0);
    convW<<<dim3(4, 512), blk, 0, stream>>>(W2, W2b, 1024, 0);
    biasperm<<<dim3(2), blk, 0, stream>>>(bq, BQp);
    biasperm<<<dim3(2), blk, 0, stream>>>(bk, BKp);
    biasperm<<<dim3(2), blk, 0, stream>>>(bv, BVp);
    transpose_cvt<<<dim3(32, 8, 4), blk, 0, stream>>>(src, X0);
    transpose_cvt<<<dim3(32, 8, 4), blk, 0, stream>>>(tgt, X1);

    dim3 g512(16, 4, 4), g1024(16, 8, 4);

    // ---- pipeline 1: q<-src(X0), k/v<-tgt(X1), residual=src ----
    gemm_bf16<<<g512, blk, 0, stream>>>(WQp, BQp, X0, nullptr, 512, 512, 512, nullptr, nullptr, B0, 0);
    gemm_bf16<<<g512, blk, 0, stream>>>(WKp, BKp, X1, nullptr, 512, 512, 512, nullptr, nullptr, B1, 0);
    gemm_bf16<<<g512, blk, 0, stream>>>(WVp, BVp, X1, nullptr, 512, 512, 512, nullptr, nullptr, B2, 1);
    attn<<<dim3(16, 8, 4), blk, 0, stream>>>(B0, B1, B2, B3);
    gemm_bf16<<<g512, blk, 0, stream>>>(WMp, bm, B3, nullptr, 512, 512, 512, nullptr, nullptr, B0, 0);
    gemm_bf16<<<g1024, blk, 0, stream>>>(W1b, b1, X0, B0, 512, 1024, 1024, nullptr, nullptr, B1, 0);
    hipMemsetAsync(STS, 0, 8192 * sizeof(float), stream);
    inorm_p1<<<dim3(16, 4, 8), blk, 0, stream>>>(B1, STS, STQ);
    inorm_p2<<<dim3(16, 4, 8), blk, 0, stream>>>(B1, STS, STQ);
    gemm_bf16<<<g512, blk, 0, stream>>>(W2b, b2, B1, nullptr, 1024, 1024, 512, src, out, B3, 2);

    // ---- pipeline 2: q<-tgt(X1), k/v<-src_new(B3), residual=tgt ----
    gemm_bf16<<<g512, blk, 0, stream>>>(WQp, BQp, X1, nullptr, 512, 512, 512, nullptr, nullptr, X0, 0);
    gemm_bf16<<<g512, blk, 0, stream>>>(WKp, BKp, B3, nullptr, 512, 512, 512, nullptr, nullptr, B0, 0);
    gemm_bf16<<<g512, blk, 0, stream>>>(WVp, BVp, B3, nullptr, 512, 512, 512, nullptr, nullptr, B1, 1);
    attn<<<dim3(16, 8, 4), blk, 0, stream>>>(X0, B0, B1, B2);
    gemm_bf16<<<g512, blk, 0, stream>>>(WMp, bm, B2, nullptr, 512, 512, 512, nullptr, nullptr, X0, 0);
    gemm_bf16<<<g1024, blk, 0, stream>>>(W1b, b1, X1, X0, 512, 1024, 1024, nullptr, nullptr, B0, 0);
    hipMemsetAsync(STS, 0, 8192 * sizeof(float), stream);
    inorm_p1<<<dim3(16, 4, 8), blk, 0, stream>>>(B0, STS, STQ);
    inorm_p2<<<dim3(16, 4, 8), blk, 0, stream>>>(B0, STS, STQ);
    gemm_bf16<<<g512, blk, 0, stream>>>(W2b, b2, B0, nullptr, 1024, 1024, 512, tgt, out + R, nullptr, 3);
}

// Round 3
// 511.939 us; speedup vs baseline: 5.0347x; 1.1730x over previous
//
#include <hip/hip_runtime.h>

#define NN 2048
#define CC 512
#define BB 4
#define HH 8
#define DD 64

typedef unsigned short u16;
typedef __attribute__((ext_vector_type(8))) short bf16x8;   // 8 bf16 (4 VGPRs)
typedef __attribute__((ext_vector_type(4))) float f32x4;    // MFMA accumulator

extern "C" __device__ float __ocml_exp2_f32(float);

__device__ inline u16 f2b(float x) {           // fp32 -> bf16 (RNE)
    unsigned u = __builtin_bit_cast(unsigned, x);
    u += 0x7fffu + ((u >> 16) & 1u);
    return (u16)(u >> 16);
}
__device__ inline float b2f(u16 h) {
    unsigned u = ((unsigned)h) << 16;
    return __builtin_bit_cast(float, u);
}

#define GLD16(g, l) __builtin_amdgcn_global_load_lds( \
    (const __attribute__((address_space(1))) unsigned int*)(g), \
    (__attribute__((address_space(3))) unsigned int*)(l), 16, 0, 0)

// ---------------------------------------------------------------------------
// GEMM core: tile 128(n) x 64(o) x 32(k), 4 waves 2x2, 8 MFMA/wave/step.
// A rows from virtual concat(Xa[..,Ca], Xb[..,K-Ca]) both [B,N,*] bf16.
// Wt = W + o0*K (64 rows, k-major).
// ---------------------------------------------------------------------------
__device__ __forceinline__ void gemm_core(
    const u16* __restrict__ Xa, const u16* __restrict__ Xb, int Ca, int K,
    const u16* __restrict__ Wt, size_t rowBase,
    u16* As, u16* Bs, f32x4 (&acc)[4][2])
{
    const int tid = threadIdx.x;
    const int lane = tid & 63, w = tid >> 6;
    const int quad = lane >> 4, l16 = lane & 15;
    const int wrow = w & 1, wcol = w >> 1;
    const int arow = lane >> 2, aseg = lane & 3;   // 16 rows x 4x16B per GLD set

    for (int k0 = 0; k0 < K; k0 += 32) {
        const u16* Xs; int Crow, cc;
        if (k0 < Ca) { Xs = Xa; Crow = Ca; cc = k0; }
        else         { Xs = Xb; Crow = K - Ca; cc = k0 - Ca; }
#pragma unroll
        for (int i = 0; i < 2; ++i) {
            int rl = w * 32 + i * 16 + arow;
            int la = __builtin_amdgcn_readfirstlane((w * 32 + i * 16) * 32);
            GLD16(Xs + (rowBase + rl) * (size_t)Crow + cc + aseg * 8, (char*)As + (size_t)la * 2);
        }
        {
            int rl = w * 16 + arow;
            int la = __builtin_amdgcn_readfirstlane((w * 16) * 32);
            GLD16(Wt + (size_t)rl * K + k0 + aseg * 8, (char*)Bs + (size_t)la * 2);
        }
        __syncthreads();
        bf16x8 av[4], bv[2];
#pragma unroll
        for (int i = 0; i < 4; ++i)
            av[i] = *(const bf16x8*)&As[(wrow * 64 + i * 16 + l16) * 32 + quad * 8];
#pragma unroll
        for (int jj = 0; jj < 2; ++jj)
            bv[jj] = *(const bf16x8*)&Bs[(wcol * 32 + jj * 16 + l16) * 32 + quad * 8];
#pragma unroll
        for (int i = 0; i < 4; ++i)
#pragma unroll
            for (int jj = 0; jj < 2; ++jj)
                acc[i][jj] = __builtin_amdgcn_mfma_f32_16x16x32_bf16(av[i], bv[jj], acc[i][jj], 0, 0, 0);
        __syncthreads();
    }
}

// mode 0: outB bf16 [B,N,Cout]
// mode 1: outB bf16 [B,H,D,N] (o=(h<<6)|d)
// mode 2: outF fp32 [B,Cout,N]=acc+bias+res AND outB bf16 [B,N,Cout]
// mode 3: outF only
__device__ __forceinline__ void gemm_epilogue(
    f32x4 (&acc)[4][2], const float* __restrict__ bias, int mode,
    int b, int n0, int o0, int Cout,
    const float* __restrict__ res, float* __restrict__ outF, u16* __restrict__ outB)
{
    const int tid = threadIdx.x;
    const int lane = tid & 63, w = tid >> 6;
    const int quad = lane >> 4, l16 = lane & 15;
    const int wrow = w & 1, wcol = w >> 1;
    const size_t bN = (size_t)b * NN;
    const int nb0 = n0 + wrow * 64, ob0 = o0 + wcol * 32;

    if (mode == 0) {
#pragma unroll
        for (int j = 0; j < 2; ++j) {
            int o = ob0 + j * 16 + l16;
            float bs = bias[o];
#pragma unroll
            for (int i = 0; i < 4; ++i)
#pragma unroll
                for (int r = 0; r < 4; ++r) {
                    int n = nb0 + i * 16 + quad * 4 + r;
                    outB[(bN + n) * Cout + o] = f2b(acc[i][j][r] + bs);
                }
        }
    } else if (mode == 1) {
#pragma unroll
        for (int j = 0; j < 2; ++j) {
            int o = ob0 + j * 16 + l16;
            float bs = bias[o];
            int h = o >> 6, d = o & 63;
#pragma unroll
            for (int i = 0; i < 4; ++i) {
                int n = nb0 + i * 16 + quad * 4;
                ushort4 pk;
                pk.x = f2b(acc[i][j][0] + bs); pk.y = f2b(acc[i][j][1] + bs);
                pk.z = f2b(acc[i][j][2] + bs); pk.w = f2b(acc[i][j][3] + bs);
                *(ushort4*)&outB[(((size_t)b * HH + h) * DD + d) * NN + n] = pk;
            }
        }
    } else {
#pragma unroll
        for (int j = 0; j < 2; ++j) {
            int o = ob0 + j * 16 + l16;
            float bs = bias[o];
#pragma unroll
            for (int i = 0; i < 4; ++i) {
                int n = nb0 + i * 16 + quad * 4;
                size_t ad = ((size_t)b * Cout + o) * NN + n;
                float4 rv = *(const float4*)&res[ad];
                float4 yv;
                yv.x = acc[i][j][0] + bs + rv.x;
                yv.y = acc[i][j][1] + bs + rv.y;
                yv.z = acc[i][j][2] + bs + rv.z;
                yv.w = acc[i][j][3] + bs + rv.w;
                *(float4*)&outF[ad] = yv;
                if (mode == 2) {
                    outB[(bN + n + 0) * Cout + o] = f2b(yv.x);
                    outB[(bN + n + 1) * Cout + o] = f2b(yv.y);
                    outB[(bN + n + 2) * Cout + o] = f2b(yv.z);
                    outB[(bN + n + 3) * Cout + o] = f2b(yv.w);
                }
            }
        }
    }
}

__global__ __launch_bounds__(256, 4) void gemm_bf16(
    const u16* __restrict__ Wb, const float* __restrict__ bias,
    const u16* __restrict__ Xa, const u16* __restrict__ Xb,
    int Ca, int K, int Cout,
    const float* __restrict__ res, float* __restrict__ outF,
    u16* __restrict__ outB, int mode)
{
    __shared__ u16 As[128 * 32];
    __shared__ u16 Bs[64 * 32];
    const int b = blockIdx.z, n0 = blockIdx.x * 128, o0 = blockIdx.y * 64;
    f32x4 acc[4][2] = {};
    gemm_core(Xa, Xb, Ca, K, Wb + (size_t)o0 * K, (size_t)b * NN + n0, As, Bs, acc);
    gemm_epilogue(acc, bias, mode, b, n0, o0, Cout, res, outF, outB);
}

// Fused Q+K+V: yb<8 -> Q from XQ; 8..15 -> K from XKV; 16..23 -> V from XKV.
__global__ __launch_bounds__(256, 4) void gemm_qkv(
    const u16* __restrict__ WQ, const float* __restrict__ bQ,
    const u16* __restrict__ XQ, u16* __restrict__ outQ,
    const u16* __restrict__ WK, const float* __restrict__ bK, u16* __restrict__ outK,
    const u16* __restrict__ WV, const float* __restrict__ bV, u16* __restrict__ outV,
    const u16* __restrict__ XKV)
{
    __shared__ u16 As[128 * 32];
    __shared__ u16 Bs[64 * 32];
    const int yb = blockIdx.y;
    const u16* W; const float* bias; const u16* X; u16* outB; int mode, o0;
    if (yb < 8)       { o0 = yb * 64;        W = WQ; bias = bQ; X = XQ;  outB = outQ; mode = 0; }
    else if (yb < 16) { o0 = (yb - 8) * 64;  W = WK; bias = bK; X = XKV; outB = outK; mode = 0; }
    else              { o0 = (yb - 16) * 64; W = WV; bias = bV; X = XKV; outB = outV; mode = 1; }
    const int b = blockIdx.z, n0 = blockIdx.x * 128;
    f32x4 acc[4][2] = {};
    gemm_core(X, nullptr, 512, 512, W + (size_t)o0 * 512, (size_t)b * NN + n0, As, Bs, acc);
    gemm_epilogue(acc, bias, mode, b, n0, o0, 512, nullptr, nullptr, outB);
}

// ---------------------------------------------------------------------------
// Flash attention, MFMA, NO max-shift (scores are O(1): softmax shift-invariant,
// exp can't overflow). Q,K: [B,N,512] bf16 head-major. V: [B,H,D,N]. Out: [B,N,512].
// l computed via P x ones MFMA -> same C-layout as O accumulator (no shfls).
// P stored truncated-bf16; truncation bias cancels in O/l ratio.
// Block = 128 q-rows; grid 512 linear, XCD-swizzled so each XCD owns 4 heads.
// ---------------------------------------------------------------------------
__global__ __launch_bounds__(256) void attn(
    const u16* __restrict__ Qg, const u16* __restrict__ Kg,
    const u16* __restrict__ Vg, u16* __restrict__ Og)
{
    __shared__ u16 Ks[64 * 72];
    __shared__ u16 Vt[64 * 72];
    __shared__ u16 Ps[128 * 72];
    const int tid = threadIdx.x;
    const int lane = tid & 63, w = tid >> 6;
    const int quad = lane >> 4, l16 = lane & 15;
    const int id = blockIdx.x;
    const int xcd = id & 7, jj = id >> 3;
    const int bh = xcd * 4 + (jj >> 4), nb = jj & 15;
    const int b = bh >> 3, h = bh & 7;
    const int n0 = nb * 128, wn0 = w * 32;
    const size_t qkBase = ((size_t)b * NN) * CC + h * DD;
    const size_t vBase  = (((size_t)b * HH + h) * DD) * NN;
    const int srow = lane >> 3, sseg = lane & 7;

    bf16x8 qf[2][2];
#pragma unroll
    for (int ct = 0; ct < 2; ++ct) {
        int n = n0 + wn0 + ct * 16 + l16;
#pragma unroll
        for (int ks = 0; ks < 2; ++ks)
            qf[ct][ks] = *(const bf16x8*)&Qg[qkBase + (size_t)n * CC + ks * 32 + quad * 8];
    }

    const short oneb = 0x3F80;
    const bf16x8 ones = {oneb, oneb, oneb, oneb, oneb, oneb, oneb, oneb};
    f32x4 oa[2][4] = {};
    f32x4 lacc[2] = {};
    const float SC = 0.18033688011112043f;   // 0.125 * log2(e)

    for (int m0 = 0; m0 < NN; m0 += 64) {
#pragma unroll
        for (int i = 0; i < 2; ++i) {
            int r = w * 16 + i * 8 + srow;
            *(bf16x8*)&Ks[r * 72 + sseg * 8] =
                *(const bf16x8*)&Kg[qkBase + (size_t)(m0 + r) * CC + sseg * 8];
            *(bf16x8*)&Vt[r * 72 + sseg * 8] =
                *(const bf16x8*)&Vg[vBase + (size_t)r * NN + m0 + sseg * 8];
        }
        __syncthreads();

        // S^T = K * Q^T : rows m (4 tiles), cols n (2 tiles)
        f32x4 st[4][2] = {};
#pragma unroll
        for (int ks = 0; ks < 2; ++ks) {
            bf16x8 ak[4];
#pragma unroll
            for (int rt = 0; rt < 4; ++rt)
                ak[rt] = *(const bf16x8*)&Ks[(rt * 16 + l16) * 72 + ks * 32 + quad * 8];
#pragma unroll
            for (int rt = 0; rt < 4; ++rt)
#pragma unroll
                for (int ct = 0; ct < 2; ++ct)
                    st[rt][ct] = __builtin_amdgcn_mfma_f32_16x16x32_bf16(ak[rt], qf[ct][ks], st[rt][ct], 0, 0, 0);
        }

        // p = exp2(s * 0.125*log2e), truncate-pack to bf16, store P[n][m]
#pragma unroll
        for (int ct = 0; ct < 2; ++ct) {
            int nrow = wn0 + ct * 16 + l16;
#pragma unroll
            for (int rt = 0; rt < 4; ++rt) {
                float p0 = __ocml_exp2_f32(st[rt][ct][0] * SC);
                float p1 = __ocml_exp2_f32(st[rt][ct][1] * SC);
                float p2 = __ocml_exp2_f32(st[rt][ct][2] * SC);
                float p3 = __ocml_exp2_f32(st[rt][ct][3] * SC);
                unsigned u0 = __builtin_bit_cast(unsigned, p0);
                unsigned u1 = __builtin_bit_cast(unsigned, p1);
                unsigned u2 = __builtin_bit_cast(unsigned, p2);
                unsigned u3 = __builtin_bit_cast(unsigned, p3);
                uint2 t;
                t.x = (u0 >> 16) | (u1 & 0xFFFF0000u);
                t.y = (u2 >> 16) | (u3 & 0xFFFF0000u);
                *(uint2*)&Ps[nrow * 72 + rt * 16 + quad * 4] = t;
            }
        }

        // O += P * V^T ; l += P * ones  (own wave's P rows -> no extra barrier)
#pragma unroll
        for (int ks = 0; ks < 2; ++ks) {
            bf16x8 pa[2], vb[4];
#pragma unroll
            for (int rt = 0; rt < 2; ++rt)
                pa[rt] = *(const bf16x8*)&Ps[(wn0 + rt * 16 + l16) * 72 + ks * 32 + quad * 8];
#pragma unroll
            for (int ct = 0; ct < 4; ++ct)
                vb[ct] = *(const bf16x8*)&Vt[(ct * 16 + l16) * 72 + ks * 32 + quad * 8];
#pragma unroll
            for (int rt = 0; rt < 2; ++rt) {
#pragma unroll
                for (int ct = 0; ct < 4; ++ct)
                    oa[rt][ct] = __builtin_amdgcn_mfma_f32_16x16x32_bf16(pa[rt], vb[ct], oa[rt][ct], 0, 0, 0);
                lacc[rt] = __builtin_amdgcn_mfma_f32_16x16x32_bf16(pa[rt], ones, lacc[rt], 0, 0, 0);
            }
        }
        __syncthreads();
    }

#pragma unroll
    for (int rt = 0; rt < 2; ++rt)
#pragma unroll
        for (int r = 0; r < 4; ++r) {
            float li = 1.f / lacc[rt][r];
            int n = n0 + wn0 + rt * 16 + quad * 4 + r;
#pragma unroll
            for (int ct = 0; ct < 4; ++ct)
                Og[qkBase + (size_t)n * CC + ct * 16 + l16] = f2b(oa[rt][ct][r] * li);
        }
}

// ---------------------------------------------------------------------------
// fp32 [B,C,N] -> bf16 [B,N,C] transpose+convert (64x64 tiles via LDS)
// ---------------------------------------------------------------------------
__global__ __launch_bounds__(256) void transpose_cvt(
    const float* __restrict__ X, u16* __restrict__ Y)
{
    __shared__ float T[64][65];
    const int tid = threadIdx.x;
    const int n0 = blockIdx.x * 64, c0 = blockIdx.y * 64, b = blockIdx.z;
    const int rr = tid >> 4, cc4 = tid & 15;
#pragma unroll
    for (int p = 0; p < 4; ++p) {
        int cl = p * 16 + rr;
        float4 v = *(const float4*)&X[((size_t)b * CC + c0 + cl) * NN + n0 + cc4 * 4];
        T[cl][cc4 * 4 + 0] = v.x; T[cl][cc4 * 4 + 1] = v.y;
        T[cl][cc4 * 4 + 2] = v.z; T[cl][cc4 * 4 + 3] = v.w;
    }
    __syncthreads();
#pragma unroll
    for (int p = 0; p < 4; ++p) {
        int nl = p * 16 + rr;
        ushort4 pk;
        pk.x = f2b(T[cc4 * 4 + 0][nl]);
        pk.y = f2b(T[cc4 * 4 + 1][nl]);
        pk.z = f2b(T[cc4 * 4 + 2][nl]);
        pk.w = f2b(T[cc4 * 4 + 3][nl]);
        *(ushort4*)&Y[((size_t)b * NN + n0 + nl) * CC + c0 + cc4 * 4] = pk;
    }
}

// Weight fp32->bf16; perm 1 = row perm (o'=h*64+d <- d*8+h), 2 = col perm.
__global__ __launch_bounds__(256) void convW(
    const float* __restrict__ W, u16* __restrict__ out, int cols, int perm)
{
    int c = blockIdx.x * 256 + threadIdx.x;
    int r = blockIdx.y;
    int sr = r, sc = c;
    if (perm == 1) sr = (r & 63) * 8 + (r >> 6);
    else if (perm == 2) sc = (c & 63) * 8 + (c >> 6);
    out[(size_t)r * cols + c] = f2b(W[(size_t)sr * cols + sc]);
}

__global__ void biasperm(const float* __restrict__ bi, float* __restrict__ o) {
    int i = blockIdx.x * 256 + threadIdx.x;
    o[i] = bi[(i & 63) * 8 + (i >> 6)];
}

// ---------------------------------------------------------------------------
// Instance norm over N per (b,c) on bf16 [B,N,1024], two-pass via fp32 atomics
// ---------------------------------------------------------------------------
__global__ __launch_bounds__(256) void inorm_p1(
    const u16* __restrict__ X, float* __restrict__ Ssum, float* __restrict__ Ssq)
{
    __shared__ float rs[4][64], rq[4][64];
    const int tid = threadIdx.x;
    const int cl = tid & 63, g = tid >> 6;
    const int c = blockIdx.x * 64 + cl;
    const int b = blockIdx.y, nz = blockIdx.z;
    float s = 0.f, q = 0.f;
    size_t base = ((size_t)b * NN + nz * 256 + g * 64) * 1024 + c;
#pragma unroll 4
    for (int i = 0; i < 64; ++i) {
        float x = b2f(X[base + (size_t)i * 1024]);
        s += x; q += x * x;
    }
    rs[g][cl] = s; rq[g][cl] = q;
    __syncthreads();
    if (g == 0) {
        s = rs[0][cl] + rs[1][cl] + rs[2][cl] + rs[3][cl];
        q = rq[0][cl] + rq[1][cl] + rq[2][cl] + rq[3][cl];
        atomicAdd(&Ssum[b * 1024 + c], s);
        atomicAdd(&Ssq[b * 1024 + c], q);
    }
}

__global__ __launch_bounds__(256) void inorm_p2(
    u16* __restrict__ X, const float* __restrict__ Ssum, const float* __restrict__ Ssq)
{
    const int tid = threadIdx.x;
    const int cl = tid & 63, g = tid >> 6;
    const int c = blockIdx.x * 64 + cl;
    const int b = blockIdx.y, nz = blockIdx.z;
    float mean = Ssum[b * 1024 + c] * (1.f / NN);
    float var  = Ssq[b * 1024 + c] * (1.f / NN) - mean * mean;
    float rstd = rsqrtf(fmaxf(var, 0.f) + 1e-5f);
    size_t base = ((size_t)b * NN + nz * 256 + g * 64) * 1024 + c;
#pragma unroll 4
    for (int i = 0; i < 64; ++i) {
        float x = b2f(X[base + (size_t)i * 1024]);
        x = (x - mean) * rstd;
        X[base + (size_t)i * 1024] = f2b(fmaxf(x, 0.f));
    }
}

// ---------------------------------------------------------------------------
extern "C" void kernel_launch(void* const* d_in, const int* in_sizes, int n_in,
                              void* d_out, int out_size, void* d_ws, size_t ws_size,
                              hipStream_t stream)
{
    (void)in_sizes; (void)n_in; (void)out_size; (void)ws_size;
    const float* src = (const float*)d_in[0];
    const float* tgt = (const float*)d_in[1];
    const float* Wq = (const float*)d_in[2];  const float* bq = (const float*)d_in[3];
    const float* Wk = (const float*)d_in[4];  const float* bk = (const float*)d_in[5];
    const float* Wv = (const float*)d_in[6];  const float* bv = (const float*)d_in[7];
    const float* Wm = (const float*)d_in[8];  const float* bm = (const float*)d_in[9];
    const float* W1 = (const float*)d_in[10]; const float* b1 = (const float*)d_in[11];
    const float* W2 = (const float*)d_in[12]; const float* b2 = (const float*)d_in[13];

    char* w = (char*)d_ws;
    u16* WQp = (u16*)(w);
    u16* WKp = (u16*)(w + (512u << 10));      // WK,WV contiguous = fused 1024x512
    u16* WVp = (u16*)(w + (1u << 20));
    u16* WMp = (u16*)(w + (3u << 19));
    u16* W1b = (u16*)(w + (2u << 20));
    u16* W2b = (u16*)(w + (4u << 20));
    float* BQp = (float*)(w + (5u << 20));
    float* BKp = BQp + 512;
    float* BVp = BQp + 1024;
    float* STS = BQp + 1536;
    float* STQ = STS + 4096;
    u16* X0 = (u16*)(w + ( 6u << 20));        // 8 MB regions
    u16* X1 = (u16*)(w + (14u << 20));
    u16* B0 = (u16*)(w + (22u << 20));
    u16* B1 = (u16*)(w + (30u << 20));        // B1+B2 = 16 MB hid region
    u16* B2 = (u16*)(w + (38u << 20));
    u16* B3 = (u16*)(w + (46u << 20));

    float* out = (float*)d_out;
    const size_t R = (size_t)BB * CC * NN;
    dim3 blk(256);

    convW<<<dim3(2, 512), blk, 0, stream>>>(Wq, WQp, 512, 1);
    convW<<<dim3(2, 512), blk, 0, stream>>>(Wk, WKp, 512, 1);
    convW<<<dim3(2, 512), blk, 0, stream>>>(Wv, WVp, 512, 1);
    convW<<<dim3(2, 512), blk, 0, stream>>>(Wm, WMp, 512, 2);
    convW<<<dim3(4, 1024), blk, 0, stream>>>(W1, W1b, 1024, 0);
    convW<<<dim3(4, 512), blk, 0, stream>>>(W2, W2b, 1024, 0);
    biasperm<<<dim3(2), blk, 0, stream>>>(bq, BQp);
    biasperm<<<dim3(2), blk, 0, stream>>>(bk, BKp);
    biasperm<<<dim3(2), blk, 0, stream>>>(bv, BVp);
    transpose_cvt<<<dim3(32, 8, 4), blk, 0, stream>>>(src, X0);
    transpose_cvt<<<dim3(32, 8, 4), blk, 0, stream>>>(tgt, X1);

    dim3 gQKV(16, 24, 4), gM(16, 8, 4), gW1(16, 16, 4), gW2(16, 8, 4);

    // ---- pipeline 1: q<-src(X0), k/v<-tgt(X1), residual=src ----
    gemm_qkv<<<gQKV, blk, 0, stream>>>(WQp, BQp, X0, B0, WKp, BKp, B1, WVp, BVp, B2, X1);
    attn<<<dim3(512), blk, 0, stream>>>(B0, B1, B2, B3);
    gemm_bf16<<<gM, blk, 0, stream>>>(WMp, bm, B3, nullptr, 512, 512, 512, nullptr, nullptr, B0, 0);
    gemm_bf16<<<gW1, blk, 0, stream>>>(W1b, b1, X0, B0, 512, 1024, 1024, nullptr, nullptr, B1, 0);
    hipMemsetAsync(STS, 0, 8192 * sizeof(float), stream);
    inorm_p1<<<dim3(16, 4, 8), blk, 0, stream>>>(B1, STS, STQ);
    inorm_p2<<<dim3(16, 4, 8), blk, 0, stream>>>(B1, STS, STQ);
    gemm_bf16<<<gW2, blk, 0, stream>>>(W2b, b2, B1, nullptr, 1024, 1024, 512, src, out, B3, 2);

    // ---- pipeline 2: q<-tgt(X1), k/v<-src_new(B3), residual=tgt ----
    gemm_qkv<<<gQKV, blk, 0, stream>>>(WQp, BQp, X1, X0, WKp, BKp, B0, WVp, BVp, B1, B3);
    attn<<<dim3(512), blk, 0, stream>>>(X0, B0, B1, B2);
    gemm_bf16<<<gM, blk, 0, stream>>>(WMp, bm, B2, nullptr, 512, 512, 512, nullptr, nullptr, X0, 0);
    gemm_bf16<<<gW1, blk, 0, stream>>>(W1b, b1, X1, X0, 512, 1024, 1024, nullptr, nullptr, B0, 0);
    hipMemsetAsync(STS, 0, 8192 * sizeof(float), stream);
    inorm_p1<<<dim3(16, 4, 8), blk, 0, stream>>>(B0, STS, STQ);
    inorm_p2<<<dim3(16, 4, 8), blk, 0, stream>>>(B0, STS, STQ);
    gemm_bf16<<<gW2, blk, 0, stream>>>(W2b, b2, B0, nullptr, 1024, 1024, 512, tgt, out + R, nullptr, 3);
}

// Round 4
// 471.305 us; speedup vs baseline: 5.4687x; 1.0862x over previous
//
#include <hip/hip_runtime.h>

#define NN 2048
#define CC 512
#define BB 4
#define HH 8
#define DD 64

typedef unsigned short u16;
typedef __attribute__((ext_vector_type(8))) short bf16x8;   // 8 bf16 (4 VGPRs)
typedef __attribute__((ext_vector_type(4))) float f32x4;    // MFMA accumulator

extern "C" __device__ float __ocml_exp2_f32(float);

__device__ inline u16 f2b(float x) {           // fp32 -> bf16 (RNE)
    unsigned u = __builtin_bit_cast(unsigned, x);
    u += 0x7fffu + ((u >> 16) & 1u);
    return (u16)(u >> 16);
}
__device__ inline float b2f(u16 h) {
    unsigned u = ((unsigned)h) << 16;
    return __builtin_bit_cast(float, u);
}

#define GLD16(g, l) __builtin_amdgcn_global_load_lds( \
    (const __attribute__((address_space(1))) unsigned int*)(g), \
    (__attribute__((address_space(3))) unsigned int*)(l), 16, 0, 0)

// ---------------------------------------------------------------------------
// GEMM core, templated output tile: 128(n) x (JT*32)(o) x 32(k).
// 4 waves 2x2; JT=2 -> 8 MFMA/wave/step (64-o tile), JT=4 -> 16 (128-o tile).
// A rows from virtual concat(Xa[..,Ca], Xb[..,K-Ca]) both [B,N,*] bf16.
// ---------------------------------------------------------------------------
template<int JT>
__device__ __forceinline__ void gemm_core_t(
    const u16* __restrict__ Xa, const u16* __restrict__ Xb, int Ca, int K,
    const u16* __restrict__ Wt, size_t rowBase,
    u16* As, u16* Bs, f32x4 (&acc)[4][JT])
{
    constexpr int OT = JT * 32;
    const int tid = threadIdx.x;
    const int lane = tid & 63, w = tid >> 6;
    const int quad = lane >> 4, l16 = lane & 15;
    const int wrow = w & 1, wcol = w >> 1;
    const int arow = lane >> 2, aseg = lane & 3;   // 16 rows x 4x16B per GLD set

    for (int k0 = 0; k0 < K; k0 += 32) {
        const u16* Xs; int Crow, cc;
        if (k0 < Ca) { Xs = Xa; Crow = Ca; cc = k0; }
        else         { Xs = Xb; Crow = K - Ca; cc = k0 - Ca; }
#pragma unroll
        for (int i = 0; i < 2; ++i) {
            int rl = w * 32 + i * 16 + arow;
            int la = __builtin_amdgcn_readfirstlane((w * 32 + i * 16) * 32);
            GLD16(Xs + (rowBase + rl) * (size_t)Crow + cc + aseg * 8, (char*)As + (size_t)la * 2);
        }
#pragma unroll
        for (int i = 0; i < OT / 64; ++i) {
            int rl = w * (OT / 4) + i * 16 + arow;
            int la = __builtin_amdgcn_readfirstlane((w * (OT / 4) + i * 16) * 32);
            GLD16(Wt + (size_t)rl * K + k0 + aseg * 8, (char*)Bs + (size_t)la * 2);
        }
        __syncthreads();
        bf16x8 av[4], bv[JT];
#pragma unroll
        for (int i = 0; i < 4; ++i)
            av[i] = *(const bf16x8*)&As[(wrow * 64 + i * 16 + l16) * 32 + quad * 8];
#pragma unroll
        for (int jj = 0; jj < JT; ++jj)
            bv[jj] = *(const bf16x8*)&Bs[(wcol * JT * 16 + jj * 16 + l16) * 32 + quad * 8];
#pragma unroll
        for (int i = 0; i < 4; ++i)
#pragma unroll
            for (int jj = 0; jj < JT; ++jj)
                acc[i][jj] = __builtin_amdgcn_mfma_f32_16x16x32_bf16(av[i], bv[jj], acc[i][jj], 0, 0, 0);
        __syncthreads();
    }
}

// mode 0: outB bf16 [B,N,Cout]
// mode 1: outB bf16 [B,H,D,N] (o=(h<<6)|d)
// mode 2: outF fp32 [B,Cout,N]=acc+bias+res AND outB bf16 [B,N,Cout]
// mode 3: outF only
template<int JT>
__device__ __forceinline__ void gemm_epilogue_t(
    f32x4 (&acc)[4][JT], const float* __restrict__ bias, int mode,
    int b, int n0, int o0, int Cout,
    const float* __restrict__ res, float* __restrict__ outF, u16* __restrict__ outB)
{
    const int tid = threadIdx.x;
    const int lane = tid & 63, w = tid >> 6;
    const int quad = lane >> 4, l16 = lane & 15;
    const int wrow = w & 1, wcol = w >> 1;
    const size_t bN = (size_t)b * NN;
    const int nb0 = n0 + wrow * 64, ob0 = o0 + wcol * JT * 16;

    if (mode == 0) {
#pragma unroll
        for (int j = 0; j < JT; ++j) {
            int o = ob0 + j * 16 + l16;
            float bs = bias[o];
#pragma unroll
            for (int i = 0; i < 4; ++i)
#pragma unroll
                for (int r = 0; r < 4; ++r) {
                    int n = nb0 + i * 16 + quad * 4 + r;
                    outB[(bN + n) * Cout + o] = f2b(acc[i][j][r] + bs);
                }
        }
    } else if (mode == 1) {
#pragma unroll
        for (int j = 0; j < JT; ++j) {
            int o = ob0 + j * 16 + l16;
            float bs = bias[o];
            int h = o >> 6, d = o & 63;
#pragma unroll
            for (int i = 0; i < 4; ++i) {
                int n = nb0 + i * 16 + quad * 4;
                ushort4 pk;
                pk.x = f2b(acc[i][j][0] + bs); pk.y = f2b(acc[i][j][1] + bs);
                pk.z = f2b(acc[i][j][2] + bs); pk.w = f2b(acc[i][j][3] + bs);
                *(ushort4*)&outB[(((size_t)b * HH + h) * DD + d) * NN + n] = pk;
            }
        }
    } else {
#pragma unroll
        for (int j = 0; j < JT; ++j) {
            int o = ob0 + j * 16 + l16;
            float bs = bias[o];
#pragma unroll
            for (int i = 0; i < 4; ++i) {
                int n = nb0 + i * 16 + quad * 4;
                size_t ad = ((size_t)b * Cout + o) * NN + n;
                float4 rv = *(const float4*)&res[ad];
                float4 yv;
                yv.x = acc[i][j][0] + bs + rv.x;
                yv.y = acc[i][j][1] + bs + rv.y;
                yv.z = acc[i][j][2] + bs + rv.z;
                yv.w = acc[i][j][3] + bs + rv.w;
                *(float4*)&outF[ad] = yv;
                if (mode == 2) {
                    outB[(bN + n + 0) * Cout + o] = f2b(yv.x);
                    outB[(bN + n + 1) * Cout + o] = f2b(yv.y);
                    outB[(bN + n + 2) * Cout + o] = f2b(yv.z);
                    outB[(bN + n + 3) * Cout + o] = f2b(yv.w);
                }
            }
        }
    }
}

template<int JT>
__global__ __launch_bounds__(256, (JT == 2 ? 4 : 3)) void gemm_bf16_t(
    const u16* __restrict__ Wb, const float* __restrict__ bias,
    const u16* __restrict__ Xa, const u16* __restrict__ Xb,
    int Ca, int K, int Cout,
    const float* __restrict__ res, float* __restrict__ outF,
    u16* __restrict__ outB, int mode)
{
    __shared__ u16 As[128 * 32];
    __shared__ u16 Bs[JT * 32 * 32];
    const int b = blockIdx.z, n0 = blockIdx.x * 128, o0 = blockIdx.y * (JT * 32);
    f32x4 acc[4][JT] = {};
    gemm_core_t<JT>(Xa, Xb, Ca, K, Wb + (size_t)o0 * K, (size_t)b * NN + n0, As, Bs, acc);
    gemm_epilogue_t<JT>(acc, bias, mode, b, n0, o0, Cout, res, outF, outB);
}

// Fused Q+K+V (128-o tiles): yb<4 -> Q from XQ; 4..7 -> K from XKV; 8..11 -> V.
__global__ __launch_bounds__(256, 3) void gemm_qkv(
    const u16* __restrict__ WQ, const float* __restrict__ bQ,
    const u16* __restrict__ XQ, u16* __restrict__ outQ,
    const u16* __restrict__ WK, const float* __restrict__ bK, u16* __restrict__ outK,
    const u16* __restrict__ WV, const float* __restrict__ bV, u16* __restrict__ outV,
    const u16* __restrict__ XKV)
{
    __shared__ u16 As[128 * 32];
    __shared__ u16 Bs[128 * 32];
    const int yb = blockIdx.y;
    const u16* W; const float* bias; const u16* X; u16* outB; int mode, o0;
    if (yb < 4)      { o0 = yb * 128;       W = WQ; bias = bQ; X = XQ;  outB = outQ; mode = 0; }
    else if (yb < 8) { o0 = (yb - 4) * 128; W = WK; bias = bK; X = XKV; outB = outK; mode = 0; }
    else             { o0 = (yb - 8) * 128; W = WV; bias = bV; X = XKV; outB = outV; mode = 1; }
    const int b = blockIdx.z, n0 = blockIdx.x * 128;
    f32x4 acc[4][4] = {};
    gemm_core_t<4>(X, nullptr, 512, 512, W + (size_t)o0 * 512, (size_t)b * NN + n0, As, Bs, acc);
    gemm_epilogue_t<4>(acc, bias, mode, b, n0, o0, 512, nullptr, nullptr, outB);
}

// ---------------------------------------------------------------------------
// Flash attention, MFMA, no max-shift (scores O(1), softmax shift-invariant).
// Q,K: [B,N,512] bf16 head-major. V: [B,H,D,N]. Out: [B,N,512].
// 64 q-rows/block (wave owns 16), m-tiles of 64 keys.
// Grid 1024 linear, XCD-swizzled: each XCD owns 4 whole heads (K/V fit its L2).
// l via P x ones MFMA -> same C-layout as O accumulator (shfl-free epilogue).
// ---------------------------------------------------------------------------
__global__ __launch_bounds__(256, 4) void attn(
    const u16* __restrict__ Qg, const u16* __restrict__ Kg,
    const u16* __restrict__ Vg, u16* __restrict__ Og)
{
    __shared__ u16 Ks[64 * 72];
    __shared__ u16 Vt[64 * 72];
    __shared__ u16 Ps[64 * 72];
    const int tid = threadIdx.x;
    const int lane = tid & 63, w = tid >> 6;
    const int quad = lane >> 4, l16 = lane & 15;
    const int id = blockIdx.x;
    const int xcd = id & 7, jj = id >> 3;
    const int bh = xcd * 4 + (jj >> 5), nb = jj & 31;
    const int b = bh >> 3, h = bh & 7;
    const int n0 = nb * 64, wn0 = w * 16;
    const size_t qkBase = ((size_t)b * NN) * CC + h * DD;
    const size_t vBase  = (((size_t)b * HH + h) * DD) * NN;
    const int srow = lane >> 3, sseg = lane & 7;

    // Q fragments (loop-invariant), B-operand layout: col=n, k=d
    bf16x8 qf[2];
    {
        int n = n0 + wn0 + l16;
#pragma unroll
        for (int ks = 0; ks < 2; ++ks)
            qf[ks] = *(const bf16x8*)&Qg[qkBase + (size_t)n * CC + ks * 32 + quad * 8];
    }

    const short oneb = 0x3F80;
    const bf16x8 ones = {oneb, oneb, oneb, oneb, oneb, oneb, oneb, oneb};
    f32x4 oa[4] = {};
    f32x4 lacc = {};
    const float SC = 0.18033688011112043f;   // 0.125 * log2(e)

    for (int m0 = 0; m0 < NN; m0 += 64) {
#pragma unroll
        for (int i = 0; i < 2; ++i) {
            int r = w * 16 + i * 8 + srow;
            *(bf16x8*)&Ks[r * 72 + sseg * 8] =
                *(const bf16x8*)&Kg[qkBase + (size_t)(m0 + r) * CC + sseg * 8];
            *(bf16x8*)&Vt[r * 72 + sseg * 8] =
                *(const bf16x8*)&Vg[vBase + (size_t)r * NN + m0 + sseg * 8];
        }
        __syncthreads();

        // S^T = K * Q^T : rows m (4 tiles of 16), cols n (this wave's 16)
        f32x4 st[4] = {};
#pragma unroll
        for (int ks = 0; ks < 2; ++ks) {
            bf16x8 ak[4];
#pragma unroll
            for (int rt = 0; rt < 4; ++rt)
                ak[rt] = *(const bf16x8*)&Ks[(rt * 16 + l16) * 72 + ks * 32 + quad * 8];
#pragma unroll
            for (int rt = 0; rt < 4; ++rt)
                st[rt] = __builtin_amdgcn_mfma_f32_16x16x32_bf16(ak[rt], qf[ks], st[rt], 0, 0, 0);
        }

        // p = exp2(s*SC), truncate-pack bf16, store P[n][m] (own wave's rows)
        {
            int nrow = wn0 + l16;
#pragma unroll
            for (int rt = 0; rt < 4; ++rt) {
                float p0 = __ocml_exp2_f32(st[rt][0] * SC);
                float p1 = __ocml_exp2_f32(st[rt][1] * SC);
                float p2 = __ocml_exp2_f32(st[rt][2] * SC);
                float p3 = __ocml_exp2_f32(st[rt][3] * SC);
                unsigned u0 = __builtin_bit_cast(unsigned, p0);
                unsigned u1 = __builtin_bit_cast(unsigned, p1);
                unsigned u2 = __builtin_bit_cast(unsigned, p2);
                unsigned u3 = __builtin_bit_cast(unsigned, p3);
                uint2 t;
                t.x = (u0 >> 16) | (u1 & 0xFFFF0000u);
                t.y = (u2 >> 16) | (u3 & 0xFFFF0000u);
                *(uint2*)&Ps[nrow * 72 + rt * 16 + quad * 4] = t;
            }
        }

        // O += P * V^T ; l += P * ones  (reads own wave's P rows, no barrier)
#pragma unroll
        for (int ks = 0; ks < 2; ++ks) {
            bf16x8 pa = *(const bf16x8*)&Ps[(wn0 + l16) * 72 + ks * 32 + quad * 8];
            bf16x8 vb[4];
#pragma unroll
            for (int ct = 0; ct < 4; ++ct)
                vb[ct] = *(const bf16x8*)&Vt[(ct * 16 + l16) * 72 + ks * 32 + quad * 8];
#pragma unroll
            for (int ct = 0; ct < 4; ++ct)
                oa[ct] = __builtin_amdgcn_mfma_f32_16x16x32_bf16(pa, vb[ct], oa[ct], 0, 0, 0);
            lacc = __builtin_amdgcn_mfma_f32_16x16x32_bf16(pa, ones, lacc, 0, 0, 0);
        }
        __syncthreads();
    }

#pragma unroll
    for (int r = 0; r < 4; ++r) {
        float li = 1.f / lacc[r];
        int n = n0 + wn0 + quad * 4 + r;
#pragma unroll
        for (int ct = 0; ct < 4; ++ct)
            Og[qkBase + (size_t)n * CC + ct * 16 + l16] = f2b(oa[ct][r] * li);
    }
}

// ---------------------------------------------------------------------------
// fp32 [B,C,N] -> bf16 [B,N,C] transpose+convert (64x64 tiles via LDS)
// ---------------------------------------------------------------------------
__global__ __launch_bounds__(256) void transpose_cvt(
    const float* __restrict__ X, u16* __restrict__ Y)
{
    __shared__ float T[64][65];
    const int tid = threadIdx.x;
    const int n0 = blockIdx.x * 64, c0 = blockIdx.y * 64, b = blockIdx.z;
    const int rr = tid >> 4, cc4 = tid & 15;
#pragma unroll
    for (int p = 0; p < 4; ++p) {
        int cl = p * 16 + rr;
        float4 v = *(const float4*)&X[((size_t)b * CC + c0 + cl) * NN + n0 + cc4 * 4];
        T[cl][cc4 * 4 + 0] = v.x; T[cl][cc4 * 4 + 1] = v.y;
        T[cl][cc4 * 4 + 2] = v.z; T[cl][cc4 * 4 + 3] = v.w;
    }
    __syncthreads();
#pragma unroll
    for (int p = 0; p < 4; ++p) {
        int nl = p * 16 + rr;
        ushort4 pk;
        pk.x = f2b(T[cc4 * 4 + 0][nl]);
        pk.y = f2b(T[cc4 * 4 + 1][nl]);
        pk.z = f2b(T[cc4 * 4 + 2][nl]);
        pk.w = f2b(T[cc4 * 4 + 3][nl]);
        *(ushort4*)&Y[((size_t)b * NN + n0 + nl) * CC + c0 + cc4 * 4] = pk;
    }
}

// Weight fp32->bf16; perm 1 = row perm (o'=h*64+d <- d*8+h), 2 = col perm.
__global__ __launch_bounds__(256) void convW(
    const float* __restrict__ W, u16* __restrict__ out, int cols, int perm)
{
    int c = blockIdx.x * 256 + threadIdx.x;
    int r = blockIdx.y;
    int sr = r, sc = c;
    if (perm == 1) sr = (r & 63) * 8 + (r >> 6);
    else if (perm == 2) sc = (c & 63) * 8 + (c >> 6);
    out[(size_t)r * cols + c] = f2b(W[(size_t)sr * cols + sc]);
}

__global__ void biasperm(const float* __restrict__ bi, float* __restrict__ o) {
    int i = blockIdx.x * 256 + threadIdx.x;
    o[i] = bi[(i & 63) * 8 + (i >> 6)];
}

// ---------------------------------------------------------------------------
// Instance norm over N per (b,c) on bf16 [B,N,1024], two-pass via fp32 atomics
// ---------------------------------------------------------------------------
__global__ __launch_bounds__(256) void inorm_p1(
    const u16* __restrict__ X, float* __restrict__ Ssum, float* __restrict__ Ssq)
{
    __shared__ float rs[4][64], rq[4][64];
    const int tid = threadIdx.x;
    const int cl = tid & 63, g = tid >> 6;
    const int c = blockIdx.x * 64 + cl;
    const int b = blockIdx.y, nz = blockIdx.z;
    float s = 0.f, q = 0.f;
    size_t base = ((size_t)b * NN + nz * 256 + g * 64) * 1024 + c;
#pragma unroll 4
    for (int i = 0; i < 64; ++i) {
        float x = b2f(X[base + (size_t)i * 1024]);
        s += x; q += x * x;
    }
    rs[g][cl] = s; rq[g][cl] = q;
    __syncthreads();
    if (g == 0) {
        s = rs[0][cl] + rs[1][cl] + rs[2][cl] + rs[3][cl];
        q = rq[0][cl] + rq[1][cl] + rq[2][cl] + rq[3][cl];
        atomicAdd(&Ssum[b * 1024 + c], s);
        atomicAdd(&Ssq[b * 1024 + c], q);
    }
}

__global__ __launch_bounds__(256) void inorm_p2(
    u16* __restrict__ X, const float* __restrict__ Ssum, const float* __restrict__ Ssq)
{
    const int tid = threadIdx.x;
    const int cl = tid & 63, g = tid >> 6;
    const int c = blockIdx.x * 64 + cl;
    const int b = blockIdx.y, nz = blockIdx.z;
    float mean = Ssum[b * 1024 + c] * (1.f / NN);
    float var  = Ssq[b * 1024 + c] * (1.f / NN) - mean * mean;
    float rstd = rsqrtf(fmaxf(var, 0.f) + 1e-5f);
    size_t base = ((size_t)b * NN + nz * 256 + g * 64) * 1024 + c;
#pragma unroll 4
    for (int i = 0; i < 64; ++i) {
        float x = b2f(X[base + (size_t)i * 1024]);
        x = (x - mean) * rstd;
        X[base + (size_t)i * 1024] = f2b(fmaxf(x, 0.f));
    }
}

// ---------------------------------------------------------------------------
extern "C" void kernel_launch(void* const* d_in, const int* in_sizes, int n_in,
                              void* d_out, int out_size, void* d_ws, size_t ws_size,
                              hipStream_t stream)
{
    (void)in_sizes; (void)n_in; (void)out_size; (void)ws_size;
    const float* src = (const float*)d_in[0];
    const float* tgt = (const float*)d_in[1];
    const float* Wq = (const float*)d_in[2];  const float* bq = (const float*)d_in[3];
    const float* Wk = (const float*)d_in[4];  const float* bk = (const float*)d_in[5];
    const float* Wv = (const float*)d_in[6];  const float* bv = (const float*)d_in[7];
    const float* Wm = (const float*)d_in[8];  const float* bm = (const float*)d_in[9];
    const float* W1 = (const float*)d_in[10]; const float* b1 = (const float*)d_in[11];
    const float* W2 = (const float*)d_in[12]; const float* b2 = (const float*)d_in[13];

    char* w = (char*)d_ws;
    u16* WQp = (u16*)(w);
    u16* WKp = (u16*)(w + (512u << 10));
    u16* WVp = (u16*)(w + (1u << 20));
    u16* WMp = (u16*)(w + (3u << 19));
    u16* W1b = (u16*)(w + (2u << 20));
    u16* W2b = (u16*)(w + (4u << 20));
    float* BQp = (float*)(w + (5u << 20));
    float* BKp = BQp + 512;
    float* BVp = BQp + 1024;
    float* STS = BQp + 1536;
    float* STQ = STS + 4096;
    u16* X0 = (u16*)(w + ( 6u << 20));        // 8 MB regions
    u16* X1 = (u16*)(w + (14u << 20));
    u16* B0 = (u16*)(w + (22u << 20));
    u16* B1 = (u16*)(w + (30u << 20));        // B1+B2 contiguous = 16 MB hid
    u16* B2 = (u16*)(w + (38u << 20));
    u16* B3 = (u16*)(w + (46u << 20));

    float* out = (float*)d_out;
    const size_t R = (size_t)BB * CC * NN;
    dim3 blk(256);

    convW<<<dim3(2, 512), blk, 0, stream>>>(Wq, WQp, 512, 1);
    convW<<<dim3(2, 512), blk, 0, stream>>>(Wk, WKp, 512, 1);
    convW<<<dim3(2, 512), blk, 0, stream>>>(Wv, WVp, 512, 1);
    convW<<<dim3(2, 512), blk, 0, stream>>>(Wm, WMp, 512, 2);
    convW<<<dim3(4, 1024), blk, 0, stream>>>(W1, W1b, 1024, 0);
    convW<<<dim3(4, 512), blk, 0, stream>>>(W2, W2b, 1024, 0);
    biasperm<<<dim3(2), blk, 0, stream>>>(bq, BQp);
    biasperm<<<dim3(2), blk, 0, stream>>>(bk, BKp);
    biasperm<<<dim3(2), blk, 0, stream>>>(bv, BVp);
    transpose_cvt<<<dim3(32, 8, 4), blk, 0, stream>>>(src, X0);
    transpose_cvt<<<dim3(32, 8, 4), blk, 0, stream>>>(tgt, X1);

    dim3 gQKV(16, 12, 4), gM(16, 8, 4), gW1(16, 8, 4), gW2(16, 8, 4);

    // ---- pipeline 1: q<-src(X0), k/v<-tgt(X1), residual=src ----
    gemm_qkv<<<gQKV, blk, 0, stream>>>(WQp, BQp, X0, B0, WKp, BKp, B1, WVp, BVp, B2, X1);
    attn<<<dim3(1024), blk, 0, stream>>>(B0, B1, B2, B3);
    gemm_bf16_t<2><<<gM, blk, 0, stream>>>(WMp, bm, B3, nullptr, 512, 512, 512, nullptr, nullptr, B0, 0);
    gemm_bf16_t<4><<<gW1, blk, 0, stream>>>(W1b, b1, X0, B0, 512, 1024, 1024, nullptr, nullptr, B1, 0);
    hipMemsetAsync(STS, 0, 8192 * sizeof(float), stream);
    inorm_p1<<<dim3(16, 4, 8), blk, 0, stream>>>(B1, STS, STQ);
    inorm_p2<<<dim3(16, 4, 8), blk, 0, stream>>>(B1, STS, STQ);
    gemm_bf16_t<2><<<gW2, blk, 0, stream>>>(W2b, b2, B1, nullptr, 1024, 1024, 512, src, out, B3, 2);

    // ---- pipeline 2: q<-tgt(X1), k/v<-src_new(B3), residual=tgt ----
    gemm_qkv<<<gQKV, blk, 0, stream>>>(WQp, BQp, X1, X0, WKp, BKp, B0, WVp, BVp, B1, B3);
    attn<<<dim3(1024), blk, 0, stream>>>(X0, B0, B1, B2);
    gemm_bf16_t<2><<<gM, blk, 0, stream>>>(WMp, bm, B2, nullptr, 512, 512, 512, nullptr, nullptr, X0, 0);
    gemm_bf16_t<4><<<gW1, blk, 0, stream>>>(W1b, b1, X1, X0, 512, 1024, 1024, nullptr, nullptr, B0, 0);
    hipMemsetAsync(STS, 0, 8192 * sizeof(float), stream);
    inorm_p1<<<dim3(16, 4, 8), blk, 0, stream>>>(B0, STS, STQ);
    inorm_p2<<<dim3(16, 4, 8), blk, 0, stream>>>(B0, STS, STQ);
    gemm_bf16_t<2><<<gW2, blk, 0, stream>>>(W2b, b2, B0, nullptr, 1024, 1024, 512, tgt, out + R, nullptr, 3);
}

// Round 5
// 448.464 us; speedup vs baseline: 5.7473x; 1.0509x over previous
//
#include <hip/hip_runtime.h>

#define NN 2048
#define CC 512
#define BB 4
#define HH 8
#define DD 64
#define SCALE 0.18033688011112043f   // 0.125 * log2(e), folded into Wq/bq

typedef unsigned short u16;
typedef __attribute__((ext_vector_type(8))) short bf16x8;   // 8 bf16 (4 VGPRs)
typedef __attribute__((ext_vector_type(4))) float f32x4;    // MFMA accumulator

extern "C" __device__ float __ocml_exp2_f32(float);

__device__ inline u16 f2b(float x) {           // fp32 -> bf16 (RNE)
    unsigned u = __builtin_bit_cast(unsigned, x);
    u += 0x7fffu + ((u >> 16) & 1u);
    return (u16)(u >> 16);
}
__device__ inline float b2f(u16 h) {
    unsigned u = ((unsigned)h) << 16;
    return __builtin_bit_cast(float, u);
}

#define GLD16(g, l) __builtin_amdgcn_global_load_lds( \
    (const __attribute__((address_space(1))) unsigned int*)(g), \
    (__attribute__((address_space(3))) unsigned int*)(l), 16, 0, 0)

// ---------------------------------------------------------------------------
// GEMM core, templated output tile: 128(n) x (JT*32)(o) x 32(k).
// 4 waves 2x2; JT=2 -> 8 MFMA/wave/step, JT=4 -> 16.
// A rows from virtual concat(Xa[..,Ca], Xb[..,K-Ca]) both [B,N,*] bf16.
// ---------------------------------------------------------------------------
template<int JT>
__device__ __forceinline__ void gemm_core_t(
    const u16* __restrict__ Xa, const u16* __restrict__ Xb, int Ca, int K,
    const u16* __restrict__ Wt, size_t rowBase,
    u16* As, u16* Bs, f32x4 (&acc)[4][JT])
{
    constexpr int OT = JT * 32;
    const int tid = threadIdx.x;
    const int lane = tid & 63, w = tid >> 6;
    const int quad = lane >> 4, l16 = lane & 15;
    const int wrow = w & 1, wcol = w >> 1;
    const int arow = lane >> 2, aseg = lane & 3;   // 16 rows x 4x16B per GLD set

    for (int k0 = 0; k0 < K; k0 += 32) {
        const u16* Xs; int Crow, cc;
        if (k0 < Ca) { Xs = Xa; Crow = Ca; cc = k0; }
        else         { Xs = Xb; Crow = K - Ca; cc = k0 - Ca; }
#pragma unroll
        for (int i = 0; i < 2; ++i) {
            int rl = w * 32 + i * 16 + arow;
            int la = __builtin_amdgcn_readfirstlane((w * 32 + i * 16) * 32);
            GLD16(Xs + (rowBase + rl) * (size_t)Crow + cc + aseg * 8, (char*)As + (size_t)la * 2);
        }
#pragma unroll
        for (int i = 0; i < OT / 64; ++i) {
            int rl = w * (OT / 4) + i * 16 + arow;
            int la = __builtin_amdgcn_readfirstlane((w * (OT / 4) + i * 16) * 32);
            GLD16(Wt + (size_t)rl * K + k0 + aseg * 8, (char*)Bs + (size_t)la * 2);
        }
        __syncthreads();
        bf16x8 av[4], bv[JT];
#pragma unroll
        for (int i = 0; i < 4; ++i)
            av[i] = *(const bf16x8*)&As[(wrow * 64 + i * 16 + l16) * 32 + quad * 8];
#pragma unroll
        for (int jj = 0; jj < JT; ++jj)
            bv[jj] = *(const bf16x8*)&Bs[(wcol * JT * 16 + jj * 16 + l16) * 32 + quad * 8];
#pragma unroll
        for (int i = 0; i < 4; ++i)
#pragma unroll
            for (int jj = 0; jj < JT; ++jj)
                acc[i][jj] = __builtin_amdgcn_mfma_f32_16x16x32_bf16(av[i], bv[jj], acc[i][jj], 0, 0, 0);
        __syncthreads();
    }
}

// mode 0: outB bf16 [B,N,Cout]
// mode 1: outB bf16 [B,H,D,N] (o=(h<<6)|d)
// mode 2: outF fp32 [B,Cout,N]=acc+bias+res AND outB bf16 [B,N,Cout]
// mode 3: outF only
template<int JT>
__device__ __forceinline__ void gemm_epilogue_t(
    f32x4 (&acc)[4][JT], const float* __restrict__ bias, int mode,
    int b, int n0, int o0, int Cout,
    const float* __restrict__ res, float* __restrict__ outF, u16* __restrict__ outB)
{
    const int tid = threadIdx.x;
    const int lane = tid & 63, w = tid >> 6;
    const int quad = lane >> 4, l16 = lane & 15;
    const int wrow = w & 1, wcol = w >> 1;
    const size_t bN = (size_t)b * NN;
    const int nb0 = n0 + wrow * 64, ob0 = o0 + wcol * JT * 16;

    if (mode == 0) {
#pragma unroll
        for (int j = 0; j < JT; ++j) {
            int o = ob0 + j * 16 + l16;
            float bs = bias[o];
#pragma unroll
            for (int i = 0; i < 4; ++i)
#pragma unroll
                for (int r = 0; r < 4; ++r) {
                    int n = nb0 + i * 16 + quad * 4 + r;
                    outB[(bN + n) * Cout + o] = f2b(acc[i][j][r] + bs);
                }
        }
    } else if (mode == 1) {
#pragma unroll
        for (int j = 0; j < JT; ++j) {
            int o = ob0 + j * 16 + l16;
            float bs = bias[o];
            int h = o >> 6, d = o & 63;
#pragma unroll
            for (int i = 0; i < 4; ++i) {
                int n = nb0 + i * 16 + quad * 4;
                ushort4 pk;
                pk.x = f2b(acc[i][j][0] + bs); pk.y = f2b(acc[i][j][1] + bs);
                pk.z = f2b(acc[i][j][2] + bs); pk.w = f2b(acc[i][j][3] + bs);
                *(ushort4*)&outB[(((size_t)b * HH + h) * DD + d) * NN + n] = pk;
            }
        }
    } else {
#pragma unroll
        for (int j = 0; j < JT; ++j) {
            int o = ob0 + j * 16 + l16;
            float bs = bias[o];
#pragma unroll
            for (int i = 0; i < 4; ++i) {
                int n = nb0 + i * 16 + quad * 4;
                size_t ad = ((size_t)b * Cout + o) * NN + n;
                float4 rv = *(const float4*)&res[ad];
                float4 yv;
                yv.x = acc[i][j][0] + bs + rv.x;
                yv.y = acc[i][j][1] + bs + rv.y;
                yv.z = acc[i][j][2] + bs + rv.z;
                yv.w = acc[i][j][3] + bs + rv.w;
                *(float4*)&outF[ad] = yv;
                if (mode == 2) {
                    outB[(bN + n + 0) * Cout + o] = f2b(yv.x);
                    outB[(bN + n + 1) * Cout + o] = f2b(yv.y);
                    outB[(bN + n + 2) * Cout + o] = f2b(yv.z);
                    outB[(bN + n + 3) * Cout + o] = f2b(yv.w);
                }
            }
        }
    }
}

template<int JT>
__global__ __launch_bounds__(256, (JT == 2 ? 4 : 3)) void gemm_bf16_t(
    const u16* __restrict__ Wb, const float* __restrict__ bias,
    const u16* __restrict__ Xa, const u16* __restrict__ Xb,
    int Ca, int K, int Cout,
    const float* __restrict__ res, float* __restrict__ outF,
    u16* __restrict__ outB, int mode)
{
    __shared__ u16 As[128 * 32];
    __shared__ u16 Bs[JT * 32 * 32];
    const int b = blockIdx.z, n0 = blockIdx.x * 128, o0 = blockIdx.y * (JT * 32);
    f32x4 acc[4][JT] = {};
    gemm_core_t<JT>(Xa, Xb, Ca, K, Wb + (size_t)o0 * K, (size_t)b * NN + n0, As, Bs, acc);
    gemm_epilogue_t<JT>(acc, bias, mode, b, n0, o0, Cout, res, outF, outB);
}

// Fused Q+K+V (128-o tiles): yb<4 -> Q from XQ; 4..7 -> K from XKV; 8..11 -> V.
__global__ __launch_bounds__(256, 3) void gemm_qkv(
    const u16* __restrict__ WQ, const float* __restrict__ bQ,
    const u16* __restrict__ XQ, u16* __restrict__ outQ,
    const u16* __restrict__ WK, const float* __restrict__ bK, u16* __restrict__ outK,
    const u16* __restrict__ WV, const float* __restrict__ bV, u16* __restrict__ outV,
    const u16* __restrict__ XKV)
{
    __shared__ u16 As[128 * 32];
    __shared__ u16 Bs[128 * 32];
    const int yb = blockIdx.y;
    const u16* W; const float* bias; const u16* X; u16* outB; int mode, o0;
    if (yb < 4)      { o0 = yb * 128;       W = WQ; bias = bQ; X = XQ;  outB = outQ; mode = 0; }
    else if (yb < 8) { o0 = (yb - 4) * 128; W = WK; bias = bK; X = XKV; outB = outK; mode = 0; }
    else             { o0 = (yb - 8) * 128; W = WV; bias = bV; X = XKV; outB = outV; mode = 1; }
    const int b = blockIdx.z, n0 = blockIdx.x * 128;
    f32x4 acc[4][4] = {};
    gemm_core_t<4>(X, nullptr, 512, 512, W + (size_t)o0 * 512, (size_t)b * NN + n0, As, Bs, acc);
    gemm_epilogue_t<4>(acc, bias, mode, b, n0, o0, 512, nullptr, nullptr, outB);
}

// ---------------------------------------------------------------------------
// Flash attention, MFMA, no max-shift (scores O(1), softmax shift-invariant).
// Q pre-scaled by 0.125*log2e at weight-prep -> p = exp2(s) directly.
// Q,K: [B,N,512] bf16 head-major. V: [B,H,D,N]. Out: [B,N,512].
// 64 q-rows/block; K/V staged via global_load_lds with XOR-swizzled 16B
// granules (g' = g ^ (row&7)) -> conflict-free reads, no padding, no VGPR
// round-trip. P uses the same swizzle. l via P x ones MFMA (C-layout epilogue).
// Grid 1024 linear, XCD-swizzled: each XCD owns 4 whole heads.
// ---------------------------------------------------------------------------
__global__ __launch_bounds__(256, 4) void attn(
    const u16* __restrict__ Qg, const u16* __restrict__ Kg,
    const u16* __restrict__ Vg, u16* __restrict__ Og)
{
    __shared__ __align__(16) u16 Ks[64 * 64];
    __shared__ __align__(16) u16 Vt[64 * 64];
    __shared__ __align__(16) u16 Ps[64 * 64];
    const int tid = threadIdx.x;
    const int lane = tid & 63, w = tid >> 6;
    const int quad = lane >> 4, l16 = lane & 15;
    const int id = blockIdx.x;
    const int xcd = id & 7, jj = id >> 3;
    const int bh = xcd * 4 + (jj >> 5), nb = jj & 31;
    const int b = bh >> 3, h = bh & 7;
    const int n0 = nb * 64, wn0 = w * 16;
    const size_t qkBase = ((size_t)b * NN) * CC + h * DD;
    const size_t vBase  = (((size_t)b * HH + h) * DD) * NN;
    const int r8 = lane >> 3, seg = lane & 7;   // staging: 8 rows x 8x16B per wave
    const int lk = l16 & 7;                     // read-side swizzle key

    // Q fragments (loop-invariant), B-operand layout: col=n, k=d
    bf16x8 qf[2];
    {
        int n = n0 + wn0 + l16;
#pragma unroll
        for (int ks = 0; ks < 2; ++ks)
            qf[ks] = *(const bf16x8*)&Qg[qkBase + (size_t)n * CC + ks * 32 + quad * 8];
    }

    const short oneb = 0x3F80;
    const bf16x8 ones = {oneb, oneb, oneb, oneb, oneb, oneb, oneb, oneb};
    f32x4 oa[4] = {};
    f32x4 lacc = {};

    for (int m0 = 0; m0 < NN; m0 += 64) {
        // swizzled direct-to-LDS staging: lane (r8,seg) fetches global granule
        // seg^r8 of row base+r8 -> LDS slot (row, seg) holds granule seg^r8
#pragma unroll
        for (int it = 0; it < 2; ++it) {
            int rowb = w * 16 + it * 8;
            int segp = seg ^ r8;
            GLD16(&Kg[qkBase + (size_t)(m0 + rowb + r8) * CC + segp * 8], &Ks[rowb * 64]);
            GLD16(&Vg[vBase + (size_t)(rowb + r8) * NN + m0 + segp * 8], &Vt[rowb * 64]);
        }
        __syncthreads();

        // S^T = K * Q^T : rows m (4 tiles of 16), cols n (this wave's 16)
        f32x4 st[4] = {};
#pragma unroll
        for (int ks = 0; ks < 2; ++ks) {
            bf16x8 ak[4];
#pragma unroll
            for (int rt = 0; rt < 4; ++rt)
                ak[rt] = *(const bf16x8*)&Ks[(rt * 16 + l16) * 64 + ((ks * 4 + quad) ^ lk) * 8];
#pragma unroll
            for (int rt = 0; rt < 4; ++rt)
                st[rt] = __builtin_amdgcn_mfma_f32_16x16x32_bf16(ak[rt], qf[ks], st[rt], 0, 0, 0);
        }

        // p = exp2(s), truncate-pack via v_perm, store P[n][m] swizzled
        {
            int nrow = wn0 + l16;
#pragma unroll
            for (int rt = 0; rt < 4; ++rt) {
                unsigned u0 = __builtin_bit_cast(unsigned, __ocml_exp2_f32(st[rt][0]));
                unsigned u1 = __builtin_bit_cast(unsigned, __ocml_exp2_f32(st[rt][1]));
                unsigned u2 = __builtin_bit_cast(unsigned, __ocml_exp2_f32(st[rt][2]));
                unsigned u3 = __builtin_bit_cast(unsigned, __ocml_exp2_f32(st[rt][3]));
                uint2 t;
                t.x = __builtin_amdgcn_perm(u1, u0, 0x07060302u);
                t.y = __builtin_amdgcn_perm(u3, u2, 0x07060302u);
                int g = (rt * 2 + (quad >> 1)) ^ lk;
                *(uint2*)&Ps[nrow * 64 + g * 8 + (quad & 1) * 4] = t;
            }
        }

        // O += P * V^T ; l += P * ones  (reads own wave's P rows, no barrier)
#pragma unroll
        for (int ks = 0; ks < 2; ++ks) {
            bf16x8 pa = *(const bf16x8*)&Ps[(wn0 + l16) * 64 + ((ks * 4 + quad) ^ lk) * 8];
            bf16x8 vb[4];
#pragma unroll
            for (int ct = 0; ct < 4; ++ct)
                vb[ct] = *(const bf16x8*)&Vt[(ct * 16 + l16) * 64 + ((ks * 4 + quad) ^ lk) * 8];
#pragma unroll
            for (int ct = 0; ct < 4; ++ct)
                oa[ct] = __builtin_amdgcn_mfma_f32_16x16x32_bf16(pa, vb[ct], oa[ct], 0, 0, 0);
            lacc = __builtin_amdgcn_mfma_f32_16x16x32_bf16(pa, ones, lacc, 0, 0, 0);
        }
        __syncthreads();
    }

#pragma unroll
    for (int r = 0; r < 4; ++r) {
        float li = 1.f / lacc[r];
        int n = n0 + wn0 + quad * 4 + r;
#pragma unroll
        for (int ct = 0; ct < 4; ++ct)
            Og[qkBase + (size_t)n * CC + ct * 16 + l16] = f2b(oa[ct][r] * li);
    }
}

// ---------------------------------------------------------------------------
// fp32 [B,C,N] -> bf16 [B,N,C] transpose+convert (64x64 tiles via LDS)
// ---------------------------------------------------------------------------
__global__ __launch_bounds__(256) void transpose_cvt(
    const float* __restrict__ X, u16* __restrict__ Y)
{
    __shared__ float T[64][65];
    const int tid = threadIdx.x;
    const int n0 = blockIdx.x * 64, c0 = blockIdx.y * 64, b = blockIdx.z;
    const int rr = tid >> 4, cc4 = tid & 15;
#pragma unroll
    for (int p = 0; p < 4; ++p) {
        int cl = p * 16 + rr;
        float4 v = *(const float4*)&X[((size_t)b * CC + c0 + cl) * NN + n0 + cc4 * 4];
        T[cl][cc4 * 4 + 0] = v.x; T[cl][cc4 * 4 + 1] = v.y;
        T[cl][cc4 * 4 + 2] = v.z; T[cl][cc4 * 4 + 3] = v.w;
    }
    __syncthreads();
#pragma unroll
    for (int p = 0; p < 4; ++p) {
        int nl = p * 16 + rr;
        ushort4 pk;
        pk.x = f2b(T[cc4 * 4 + 0][nl]);
        pk.y = f2b(T[cc4 * 4 + 1][nl]);
        pk.z = f2b(T[cc4 * 4 + 2][nl]);
        pk.w = f2b(T[cc4 * 4 + 3][nl]);
        *(ushort4*)&Y[((size_t)b * NN + n0 + nl) * CC + c0 + cc4 * 4] = pk;
    }
}

// ---------------------------------------------------------------------------
// One-shot weight prep: fp32->bf16 with optional row/col head-permute + scale.
// z: 0=Wq(perm1,xSCALE) 1=Wk(perm1) 2=Wv(perm1) 3=Wm(perm2) 4=W1 5=W2
// ---------------------------------------------------------------------------
__global__ __launch_bounds__(256) void prep_weights(
    const float* __restrict__ Wq, const float* __restrict__ Wk,
    const float* __restrict__ Wv, const float* __restrict__ Wm,
    const float* __restrict__ W1, const float* __restrict__ W2,
    u16* oQ, u16* oK, u16* oV, u16* oM, u16* o1, u16* o2)
{
    const float* W; u16* o; int rows, cols, perm; float sc = 1.f;
    switch (blockIdx.z) {
        case 0: W = Wq; o = oQ; rows = 512;  cols = 512;  perm = 1; sc = SCALE; break;
        case 1: W = Wk; o = oK; rows = 512;  cols = 512;  perm = 1; break;
        case 2: W = Wv; o = oV; rows = 512;  cols = 512;  perm = 1; break;
        case 3: W = Wm; o = oM; rows = 512;  cols = 512;  perm = 2; break;
        case 4: W = W1; o = o1; rows = 1024; cols = 1024; perm = 0; break;
        default: W = W2; o = o2; rows = 512; cols = 1024; perm = 0; break;
    }
    int c = blockIdx.x * 256 + threadIdx.x;
    int r = blockIdx.y;
    if (r >= rows || c >= cols) return;
    int sr = r, scol = c;
    if (perm == 1) sr = (r & 63) * 8 + (r >> 6);
    else if (perm == 2) scol = (c & 63) * 8 + (c >> 6);
    o[(size_t)r * cols + c] = f2b(W[(size_t)sr * cols + scol] * sc);
}

__global__ void prep_bias(const float* __restrict__ bq, const float* __restrict__ bk,
                          const float* __restrict__ bv,
                          float* oq, float* ok, float* ov)
{
    int i = blockIdx.x * 256 + threadIdx.x;
    int y = blockIdx.y;
    const float* s = (y == 0) ? bq : (y == 1) ? bk : bv;
    float* o = (y == 0) ? oq : (y == 1) ? ok : ov;
    float v = s[(i & 63) * 8 + (i >> 6)];
    if (y == 0) v *= SCALE;
    o[i] = v;
}

// ---------------------------------------------------------------------------
// Instance norm over N per (b,c) on bf16 [B,N,1024], two-pass via fp32 atomics
// ---------------------------------------------------------------------------
__global__ __launch_bounds__(256) void inorm_p1(
    const u16* __restrict__ X, float* __restrict__ Ssum, float* __restrict__ Ssq)
{
    __shared__ float rs[4][64], rq[4][64];
    const int tid = threadIdx.x;
    const int cl = tid & 63, g = tid >> 6;
    const int c = blockIdx.x * 64 + cl;
    const int b = blockIdx.y, nz = blockIdx.z;
    float s = 0.f, q = 0.f;
    size_t base = ((size_t)b * NN + nz * 256 + g * 64) * 1024 + c;
#pragma unroll 4
    for (int i = 0; i < 64; ++i) {
        float x = b2f(X[base + (size_t)i * 1024]);
        s += x; q += x * x;
    }
    rs[g][cl] = s; rq[g][cl] = q;
    __syncthreads();
    if (g == 0) {
        s = rs[0][cl] + rs[1][cl] + rs[2][cl] + rs[3][cl];
        q = rq[0][cl] + rq[1][cl] + rq[2][cl] + rq[3][cl];
        atomicAdd(&Ssum[b * 1024 + c], s);
        atomicAdd(&Ssq[b * 1024 + c], q);
    }
}

__global__ __launch_bounds__(256) void inorm_p2(
    u16* __restrict__ X, const float* __restrict__ Ssum, const float* __restrict__ Ssq)
{
    const int tid = threadIdx.x;
    const int cl = tid & 63, g = tid >> 6;
    const int c = blockIdx.x * 64 + cl;
    const int b = blockIdx.y, nz = blockIdx.z;
    float mean = Ssum[b * 1024 + c] * (1.f / NN);
    float var  = Ssq[b * 1024 + c] * (1.f / NN) - mean * mean;
    float rstd = rsqrtf(fmaxf(var, 0.f) + 1e-5f);
    size_t base = ((size_t)b * NN + nz * 256 + g * 64) * 1024 + c;
#pragma unroll 4
    for (int i = 0; i < 64; ++i) {
        float x = b2f(X[base + (size_t)i * 1024]);
        x = (x - mean) * rstd;
        X[base + (size_t)i * 1024] = f2b(fmaxf(x, 0.f));
    }
}

// ---------------------------------------------------------------------------
extern "C" void kernel_launch(void* const* d_in, const int* in_sizes, int n_in,
                              void* d_out, int out_size, void* d_ws, size_t ws_size,
                              hipStream_t stream)
{
    (void)in_sizes; (void)n_in; (void)out_size; (void)ws_size;
    const float* src = (const float*)d_in[0];
    const float* tgt = (const float*)d_in[1];
    const float* Wq = (const float*)d_in[2];  const float* bq = (const float*)d_in[3];
    const float* Wk = (const float*)d_in[4];  const float* bk = (const float*)d_in[5];
    const float* Wv = (const float*)d_in[6];  const float* bv = (const float*)d_in[7];
    const float* Wm = (const float*)d_in[8];  const float* bm = (const float*)d_in[9];
    const float* W1 = (const float*)d_in[10]; const float* b1 = (const float*)d_in[11];
    const float* W2 = (const float*)d_in[12]; const float* b2 = (const float*)d_in[13];

    char* w = (char*)d_ws;
    u16* WQp = (u16*)(w);
    u16* WKp = (u16*)(w + (512u << 10));
    u16* WVp = (u16*)(w + (1u << 20));
    u16* WMp = (u16*)(w + (3u << 19));
    u16* W1b = (u16*)(w + (2u << 20));
    u16* W2b = (u16*)(w + (4u << 20));
    float* BQp = (float*)(w + (5u << 20));
    float* BKp = BQp + 512;
    float* BVp = BQp + 1024;
    float* STS = BQp + 1536;
    float* STQ = STS + 4096;
    u16* X0 = (u16*)(w + ( 6u << 20));        // 8 MB regions
    u16* X1 = (u16*)(w + (14u << 20));
    u16* B0 = (u16*)(w + (22u << 20));
    u16* B1 = (u16*)(w + (30u << 20));
    u16* B2 = (u16*)(w + (38u << 20));
    u16* B3 = (u16*)(w + (46u << 20));

    float* out = (float*)d_out;
    const size_t R = (size_t)BB * CC * NN;
    dim3 blk(256);

    prep_weights<<<dim3(4, 1024, 6), blk, 0, stream>>>(Wq, Wk, Wv, Wm, W1, W2,
                                                       WQp, WKp, WVp, WMp, W1b, W2b);
    prep_bias<<<dim3(2, 3), blk, 0, stream>>>(bq, bk, bv, BQp, BKp, BVp);
    transpose_cvt<<<dim3(32, 8, 4), blk, 0, stream>>>(src, X0);
    transpose_cvt<<<dim3(32, 8, 4), blk, 0, stream>>>(tgt, X1);

    dim3 gQKV(16, 12, 4), gM(16, 8, 4), gW1(16, 8, 4), gW2(16, 8, 4);

    // ---- pipeline 1: q<-src(X0), k/v<-tgt(X1), residual=src ----
    gemm_qkv<<<gQKV, blk, 0, stream>>>(WQp, BQp, X0, B0, WKp, BKp, B1, WVp, BVp, B2, X1);
    attn<<<dim3(1024), blk, 0, stream>>>(B0, B1, B2, B3);
    gemm_bf16_t<2><<<gM, blk, 0, stream>>>(WMp, bm, B3, nullptr, 512, 512, 512, nullptr, nullptr, B0, 0);
    gemm_bf16_t<4><<<gW1, blk, 0, stream>>>(W1b, b1, X0, B0, 512, 1024, 1024, nullptr, nullptr, B1, 0);
    hipMemsetAsync(STS, 0, 8192 * sizeof(float), stream);
    inorm_p1<<<dim3(16, 4, 8), blk, 0, stream>>>(B1, STS, STQ);
    inorm_p2<<<dim3(16, 4, 8), blk, 0, stream>>>(B1, STS, STQ);
    gemm_bf16_t<2><<<gW2, blk, 0, stream>>>(W2b, b2, B1, nullptr, 1024, 1024, 512, src, out, B3, 2);

    // ---- pipeline 2: q<-tgt(X1), k/v<-src_new(B3), residual=tgt ----
    gemm_qkv<<<gQKV, blk, 0, stream>>>(WQp, BQp, X1, X0, WKp, BKp, B0, WVp, BVp, B1, B3);
    attn<<<dim3(1024), blk, 0, stream>>>(X0, B0, B1, B2);
    gemm_bf16_t<2><<<gM, blk, 0, stream>>>(WMp, bm, B2, nullptr, 512, 512, 512, nullptr, nullptr, X0, 0);
    gemm_bf16_t<4><<<gW1, blk, 0, stream>>>(W1b, b1, X1, X0, 512, 1024, 1024, nullptr, nullptr, B0, 0);
    hipMemsetAsync(STS, 0, 8192 * sizeof(float), stream);
    inorm_p1<<<dim3(16, 4, 8), blk, 0, stream>>>(B0, STS, STQ);
    inorm_p2<<<dim3(16, 4, 8), blk, 0, stream>>>(B0, STS, STQ);
    gemm_bf16_t<2><<<gW2, blk, 0, stream>>>(W2b, b2, B0, nullptr, 1024, 1024, 512, tgt, out + R, nullptr, 3);
}